// Round 12
// baseline (4078.412 us; speedup 1.0000x reference)
//
#include <hip/hip_runtime.h>
#include <math.h>
#include <float.h>

#define NN 100000
#define EE 1000000
#define CC 64
#define HH 4
#define DD 16
#define LL 4
#define TT 3
#define RR 5
#define NB 196          // CSR buckets: 512 dsts each (196*512 >= NN)
#define PR 64           // row-tile for GEMM-family kernels

__device__ __constant__ int g_dst[RR]   = {0, 1, 0, 2, 0};
__device__ __constant__ int g_first[RR] = {1, 1, 0, 1, 0};

__device__ __forceinline__ float geluf(float x) {
    return 0.5f * x * (1.0f + erff(x * 0.7071067811865476f));
}

__global__ void zero_out_kernel(float* out) {
    if (threadIdx.x == 0 && blockIdx.x == 0) out[0] = 0.f;
}

__device__ __forceinline__ const int* sel_edge(int r, const int* p0, const int* p1,
                                               const int* p2, const int* p3, const int* p4) {
    return (r == 0) ? p0 : (r == 1) ? p1 : (r == 2) ? p2 : (r == 3) ? p3 : p4;
}

// ---------------- fuse Q weights with a_rel^T: WQE = Wq @ blockdiag(A^T) per (l,r) ------
__global__ __launch_bounds__(256) void fuse_q(
    const float* __restrict__ Wq, const float* __restrict__ bq,
    const float* __restrict__ a_rel,
    float* __restrict__ WQE, float* __restrict__ BQE)
{
    int lr = blockIdx.x;            // l*RR + r
    int l = lr / RR, r = lr % RR;
    int d = g_dst[r];
    const float* W  = Wq + (size_t)(l * TT + d) * CC * CC;
    const float* bb = bq + (size_t)(l * TT + d) * CC;
    const float* A  = a_rel + (size_t)lr * HH * DD * DD;
    float* Wo = WQE + (size_t)lr * CC * CC;
    float* bo = BQE + (size_t)lr * CC;

    for (int i = threadIdx.x; i < CC * CC; i += 256) {
        int c = i >> 6, j = i & 63, h = j >> 4, dout = j & 15;
        float acc = 0.f;
        #pragma unroll
        for (int e0 = 0; e0 < DD; ++e0)
            acc += W[c * CC + h * DD + e0] * A[(h * DD + dout) * DD + e0];
        Wo[i] = acc;
    }
    if (threadIdx.x < CC) {
        int j = threadIdx.x, h = j >> 4, dout = j & 15;
        float acc = 0.f;
        #pragma unroll
        for (int e0 = 0; e0 < DD; ++e0)
            acc += bb[h * DD + e0] * A[(h * DD + dout) * DD + e0];
        bo[j] = acc;
    }
}

// ================= CSR build: bucketed two-phase counting sort =================
__global__ __launch_bounds__(256) void bucket_hist(
    const int* __restrict__ p0, const int* __restrict__ p1, const int* __restrict__ p2,
    const int* __restrict__ p3, const int* __restrict__ p4, int* __restrict__ bcnt)
{
    int r = blockIdx.y;
    const int* col = sel_edge(r, p0, p1, p2, p3, p4) + EE;
    __shared__ int lh[256];
    int tid = threadIdx.x;
    lh[tid] = 0;
    __syncthreads();
    int base = blockIdx.x * 4096;
    for (int i = tid; i < 4096; i += 256) {
        int g = base + i;
        if (g < EE) atomicAdd(&lh[col[g] >> 9], 1);
    }
    __syncthreads();
    if (tid < NB && lh[tid]) atomicAdd(&bcnt[r * NB + tid], lh[tid]);
}

__global__ __launch_bounds__(256) void bucket_scan(
    const int* __restrict__ bcnt, int* __restrict__ bbase, int* __restrict__ gcur,
    int* __restrict__ indptr)
{
    int r = blockIdx.x;
    __shared__ int ls[256];
    int tid = threadIdx.x;
    ls[tid] = (tid < NB) ? bcnt[r * NB + tid] : 0;
    __syncthreads();
    for (int o = 1; o < 256; o <<= 1) {
        int v = (tid >= o) ? ls[tid - o] : 0;
        __syncthreads();
        ls[tid] += v;
        __syncthreads();
    }
    int ex = (tid == 0) ? 0 : ls[tid - 1];
    if (tid < NB) {
        bbase[r * (NB + 1) + tid] = ex;
        gcur[r * NB + tid] = ex;
    }
    if (tid == NB) bbase[r * (NB + 1) + NB] = ls[NB - 1];   // == EE
    if (tid == 0) indptr[(size_t)r * (NN + 1) + NN] = EE;
}

// P2: partition packed (col_local<<17 | row) into bucket-contiguous runs
__global__ __launch_bounds__(256) void bucket_partition(
    const int* __restrict__ p0, const int* __restrict__ p1, const int* __restrict__ p2,
    const int* __restrict__ p3, const int* __restrict__ p4,
    int* __restrict__ gcur, unsigned* __restrict__ pairs)
{
    int r = blockIdx.y;
    const int* ebase = sel_edge(r, p0, p1, p2, p3, p4);
    const int* colp = ebase + EE;
    __shared__ int2 stag[4096];
    __shared__ int lh[256], lofs[256], lcur[256], gpos[256];
    int tid = threadIdx.x;
    lh[tid] = 0;
    __syncthreads();
    int base = blockIdx.x * 4096;
    for (int i = tid; i < 4096; i += 256) {
        int g = base + i;
        if (g < EE) atomicAdd(&lh[colp[g] >> 9], 1);
    }
    __syncthreads();
    lofs[tid] = lh[tid];
    __syncthreads();
    for (int o = 1; o < 256; o <<= 1) {
        int v = (tid >= o) ? lofs[tid - o] : 0;
        __syncthreads();
        lofs[tid] += v;
        __syncthreads();
    }
    int ex = (tid == 0) ? 0 : lofs[tid - 1];
    __syncthreads();
    lofs[tid] = ex;
    lcur[tid] = ex;
    gpos[tid] = (lh[tid] > 0) ? atomicAdd(&gcur[r * NB + tid], lh[tid]) : 0;
    __syncthreads();
    for (int i = tid; i < 4096; i += 256) {
        int g = base + i;
        if (g < EE) {
            int c = colp[g];
            int b = c >> 9;
            int s = atomicAdd(&lcur[b], 1);
            stag[s] = make_int2(ebase[g], c);
        }
    }
    __syncthreads();
    int total = EE - base; if (total > 4096) total = 4096;
    for (int s = tid; s < total; s += 256) {
        int2 pr = stag[s];
        int b = pr.y >> 9;
        unsigned packed = ((unsigned)(pr.y & 511) << 17) | (unsigned)pr.x;
        pairs[(size_t)r * EE + gpos[b] + (s - lofs[b])] = packed;
    }
}

__global__ __launch_bounds__(256) void bucket_finalize(
    const unsigned* __restrict__ pairs, const int* __restrict__ bbase,
    int* __restrict__ indptr, int* __restrict__ rowsrt)
{
    int r = blockIdx.y, b = blockIdx.x;
    int beg = bbase[r * (NB + 1) + b], end = bbase[r * (NB + 1) + b + 1];
    int d0 = b << 9;
    int nd = NN - d0; if (nd > 512) nd = 512;
    __shared__ int cnt[512];
    __shared__ int exc[512];
    __shared__ int ls[256];
    int tid = threadIdx.x;
    cnt[tid] = 0; cnt[tid + 256] = 0;
    __syncthreads();
    const unsigned* pp = pairs + (size_t)r * EE;
    for (int e = beg + tid; e < end; e += 256)
        atomicAdd(&cnt[pp[e] >> 17], 1);
    __syncthreads();
    int a0 = cnt[2 * tid], a1 = cnt[2 * tid + 1];
    ls[tid] = a0 + a1;
    __syncthreads();
    for (int o = 1; o < 256; o <<= 1) {
        int v = (tid >= o) ? ls[tid - o] : 0;
        __syncthreads();
        ls[tid] += v;
        __syncthreads();
    }
    int ex2 = (tid == 0) ? 0 : ls[tid - 1];
    exc[2 * tid] = ex2;
    exc[2 * tid + 1] = ex2 + a0;
    __syncthreads();
    for (int i = tid; i < nd; i += 256)
        indptr[(size_t)r * (NN + 1) + d0 + i] = beg + exc[i];
    cnt[2 * tid] = exc[2 * tid];
    cnt[2 * tid + 1] = exc[2 * tid + 1];
    __syncthreads();
    for (int e = beg + tid; e < end; e += 256) {
        unsigned pr = pp[e];
        int p = atomicAdd(&cnt[pr >> 17], 1);
        rowsrt[(size_t)r * EE + beg + p] = (int)(pr & 0x1FFFFu);
    }
}

// ================= degree-sorted node order (counting sort, 256 deg bins) ==============
__global__ void deg_hist(const int* __restrict__ indptr, int* __restrict__ dbin)
{
    int r = blockIdx.y;
    int i = blockIdx.x * 256 + threadIdx.x;
    if (i < NN) {
        const int* ip = indptr + (size_t)r * (NN + 1);
        int deg = ip[i + 1] - ip[i];
        if (deg > 255) deg = 255;
        atomicAdd(&dbin[r * 256 + deg], 1);
    }
}

__global__ __launch_bounds__(256) void deg_scan(int* __restrict__ dbin)
{
    int r = blockIdx.x;
    __shared__ int ls[256];
    int tid = threadIdx.x;
    ls[tid] = dbin[r * 256 + tid];
    __syncthreads();
    for (int o = 1; o < 256; o <<= 1) {
        int v = (tid >= o) ? ls[tid - o] : 0;
        __syncthreads();
        ls[tid] += v;
        __syncthreads();
    }
    dbin[r * 256 + tid] = (tid == 0) ? 0 : ls[tid - 1];   // exclusive
}

__global__ void deg_scatter(const int* __restrict__ indptr, int* __restrict__ dbin,
                            int* __restrict__ order)
{
    int r = blockIdx.y;
    int i = blockIdx.x * 256 + threadIdx.x;
    if (i < NN) {
        const int* ip = indptr + (size_t)r * (NN + 1);
        int deg = ip[i + 1] - ip[i];
        if (deg > 255) deg = 255;
        int pos = atomicAdd(&dbin[r * 256 + deg], 1);
        order[(size_t)r * NN + pos] = i;
    }
}

// ---------------- fused K+V projection (per TYPE) -> KV[node][0:64]=K, [64:128]=V ------
__global__ __launch_bounds__(256) void projKV_kernel(
    const float* __restrict__ X,
    const float* __restrict__ WK, const float* __restrict__ BK,
    const float* __restrict__ WV, const float* __restrict__ BV,
    float* __restrict__ KV, int nrows)
{
    __shared__ float Xs[PR][CC + 1];
    __shared__ float WKs[CC][CC];
    __shared__ float WVs[CC][CC];
    __shared__ float bks[CC], bvs[CC];
    int tid = threadIdx.x;
    int row0 = blockIdx.x * PR;
    for (int i = tid; i < CC * CC; i += 256) {
        WKs[i >> 6][i & 63] = WK[i];
        WVs[i >> 6][i & 63] = WV[i];
    }
    if (tid < CC) { bks[tid] = BK[tid]; bvs[tid] = BV[tid]; }
    for (int i = tid; i < PR * CC; i += 256) {
        int r = i >> 6, c = i & 63;
        int gr = row0 + r;
        Xs[r][c] = (gr < nrows) ? X[(size_t)gr * CC + c] : 0.f;
    }
    __syncthreads();
    int tx = tid & 15, ty = tid >> 4;
    float aK[4][4], aV[4][4];
    #pragma unroll
    for (int i = 0; i < 4; ++i)
        #pragma unroll
        for (int j = 0; j < 4; ++j) { aK[i][j] = 0.f; aV[i][j] = 0.f; }
    for (int k = 0; k < CC; ++k) {
        float xv[4], wk4[4], wv4[4];
        #pragma unroll
        for (int i = 0; i < 4; ++i) xv[i] = Xs[ty + 16 * i][k];
        #pragma unroll
        for (int j = 0; j < 4; ++j) { wk4[j] = WKs[k][tx + 16 * j]; wv4[j] = WVs[k][tx + 16 * j]; }
        #pragma unroll
        for (int i = 0; i < 4; ++i)
            #pragma unroll
            for (int j = 0; j < 4; ++j) {
                aK[i][j] += xv[i] * wk4[j];
                aV[i][j] += xv[i] * wv4[j];
            }
    }
    #pragma unroll
    for (int i = 0; i < 4; ++i) {
        int r = row0 + ty + 16 * i;
        if (r < nrows) {
            #pragma unroll
            for (int j = 0; j < 4; ++j) {
                int c = tx + 16 * j;
                KV[(size_t)r * 128 + c]      = aK[i][j] + bks[c];
                KV[(size_t)r * 128 + 64 + c] = aV[i][j] + bvs[c];
            }
        }
    }
}

// ---------------- edge pass: degree-sorted nodes; 4 dst nodes/wave ---------------------
__global__ __launch_bounds__(256) void edge_kernel(
    const int* __restrict__ indptr_all, const int* __restrict__ rows_all,
    const int* __restrict__ order_all,
    const float* __restrict__ x0, const float* __restrict__ x1, const float* __restrict__ x2,
    const float* __restrict__ WQE_l, const float* __restrict__ BQE_l,
    const float* __restrict__ kv, const float* __restrict__ Mrel_l,
    const float* __restrict__ prel_l,
    float* __restrict__ outb, int r0)
{
    int ri = blockIdx.y;
    int r = r0 + ri;
    int d = g_dst[r];
    const float* xd = (d == 0) ? x0 : (d == 1) ? x1 : x2;
    const int* indptr = indptr_all + (size_t)r * (NN + 1);
    const int* rows = rows_all + (size_t)r * EE;
    const int* order = order_all + (size_t)r * NN;
    const float* Wq = WQE_l + (size_t)ri * CC * CC;
    const float* bqp = BQE_l + (size_t)ri * CC;
    const float* Mrel = Mrel_l + (size_t)ri * HH * DD * DD;
    const float* prel = prel_l + (size_t)ri * HH;
    float* outp = outb + (size_t)d * NN * CC;
    int accum = 1 - g_first[r];

    __shared__ float4 Wq4s[CC][16];    // 16 KB
    __shared__ float  xs[16][CC + 4];  // padded: groups hit distinct banks
    __shared__ float4 bq4s[16];
    int tid = threadIdx.x;
    const float4* Wq4 = (const float4*)Wq;
    for (int i = tid; i < CC * 16; i += 256)
        Wq4s[i >> 4][i & 15] = Wq4[i];
    if (tid < 16) bq4s[tid] = ((const float4*)bqp)[tid];

    int g = tid >> 4;                 // node slot 0..15
    int gl = tid & 15;                // lane in group: channels 4gl..4gl+3
    int node = order[blockIdx.x * 16 + g];   // degree-sorted permutation
    {
        float4 xv4 = ((const float4*)xd)[(size_t)node * 16 + gl];
        ((float4*)&xs[g][0])[gl] = xv4;
    }
    __syncthreads();

    int h = gl >> 2;
    float ps = prel[h] * (0.25f * 1.4426950408889634f);

    float4 q4 = bq4s[gl];
    #pragma unroll 8
    for (int k = 0; k < CC; ++k) {
        float xk = xs[g][k];
        float4 w = Wq4s[k][gl];
        q4.x += xk * w.x; q4.y += xk * w.y; q4.z += xk * w.z; q4.w += xk * w.w;
    }

    int beg = indptr[node], end = indptr[node + 1];
    float m = -INFINITY, ss = 0.f;
    float4 o4 = make_float4(0.f, 0.f, 0.f, 0.f);
    const float4* kv4 = (const float4*)kv;
    for (int e = beg; e < end; ++e) {
        int rr = rows[e];
        const float4* kp = kv4 + (size_t)rr * 32;
        float4 k4 = kp[gl];
        float4 v4 = kp[16 + gl];
        float p = q4.x * k4.x + q4.y * k4.y + q4.z * k4.z + q4.w * k4.w;
        p += __shfl_xor(p, 1, 4);
        p += __shfl_xor(p, 2, 4);
        float al = p * ps;
        float nm = fmaxf(m, al);
        float sc = exp2f(m - nm);
        float ei = exp2f(al - nm);
        ss = ss * sc + ei;
        o4.x = o4.x * sc + ei * v4.x;
        o4.y = o4.y * sc + ei * v4.y;
        o4.z = o4.z * sc + ei * v4.z;
        o4.w = o4.w * sc + ei * v4.w;
        m = nm;
    }
    float inv = 1.f / (ss + 1e-16f);
    float4 res = make_float4(o4.x * inv, o4.y * inv, o4.z * inv, o4.w * inv);

    // out[h,e] = sum_d res[h,d] * M[h][d][e]  (M from global: 4 KB, L2-hot)
    const float4* Ms4 = (const float4*)Mrel;
    float4 out4 = make_float4(0.f, 0.f, 0.f, 0.f);
    int e4 = gl & 3;
    #pragma unroll
    for (int sl = 0; sl < 4; ++sl) {
        int src = (gl & 12) + sl;
        float a0 = __shfl(res.x, src, 16);
        float a1 = __shfl(res.y, src, 16);
        float a2 = __shfl(res.z, src, 16);
        float a3 = __shfl(res.w, src, 16);
        float4 m0 = Ms4[(h * DD + sl * 4 + 0) * 4 + e4];
        float4 m1 = Ms4[(h * DD + sl * 4 + 1) * 4 + e4];
        float4 m2 = Ms4[(h * DD + sl * 4 + 2) * 4 + e4];
        float4 m3 = Ms4[(h * DD + sl * 4 + 3) * 4 + e4];
        out4.x += a0 * m0.x + a1 * m1.x + a2 * m2.x + a3 * m3.x;
        out4.y += a0 * m0.y + a1 * m1.y + a2 * m2.y + a3 * m3.y;
        out4.z += a0 * m0.z + a1 * m1.z + a2 * m2.z + a3 * m3.z;
        out4.w += a0 * m0.w + a1 * m1.w + a2 * m2.w + a3 * m3.w;
    }

    float4* op = (float4*)outp + (size_t)node * 16;
    if (accum) {
        float4 old = op[gl];
        out4.x += old.x; out4.y += old.y; out4.z += old.z; out4.w += old.w;
    }
    op[gl] = out4;
}

// ---------------- post: 64-row GEMM tile + fused skip/LN/gelu --------------------------
__global__ __launch_bounds__(256) void post3_kernel(
    const float* __restrict__ x0, const float* __restrict__ x1, const float* __restrict__ x2,
    const float* __restrict__ outc, float* __restrict__ xout,
    const float* __restrict__ Wa_l, const float* __restrict__ ba_l,
    const float* __restrict__ skp_l,
    const float* __restrict__ lnw_l, const float* __restrict__ lnb_l)
{
    int t = blockIdx.y;
    const float* xin = (t == 0) ? x0 : (t == 1) ? x1 : x2;
    const float* Wa = Wa_l + (size_t)t * CC * CC;
    const float* ba = ba_l + (size_t)t * CC;
    const float* lnw = lnw_l + (size_t)t * CC;
    const float* lnb = lnb_l + (size_t)t * CC;
    const float* oc = outc + (size_t)t * NN * CC;
    float* xo = xout + (size_t)t * NN * CC;

    __shared__ float Gs[PR][CC + 1];
    __shared__ float Was[CC][CC];
    __shared__ float bas[CC], lnws[CC], lnbs[CC];
    int tid = threadIdx.x;
    int row0 = blockIdx.x * PR;
    for (int i = tid; i < CC * CC; i += 256) Was[i >> 6][i & 63] = Wa[i];
    if (tid < CC) { bas[tid] = ba[tid]; lnws[tid] = lnw[tid]; lnbs[tid] = lnb[tid]; }
    for (int i = tid; i < PR * CC; i += 256) {
        int r = i >> 6, c = i & 63;
        int gr = row0 + r;
        Gs[r][c] = (gr < NN) ? geluf(oc[(size_t)gr * CC + c]) : 0.f;
    }
    __syncthreads();
    int tx = tid & 15, ty = tid >> 4;
    float acc[4][4];
    #pragma unroll
    for (int i = 0; i < 4; ++i)
        #pragma unroll
        for (int j = 0; j < 4; ++j) acc[i][j] = 0.f;
    for (int k = 0; k < CC; ++k) {
        float gv[4], w4[4];
        #pragma unroll
        for (int i = 0; i < 4; ++i) gv[i] = Gs[ty + 16 * i][k];
        #pragma unroll
        for (int j = 0; j < 4; ++j) w4[j] = Was[k][tx + 16 * j];
        #pragma unroll
        for (int i = 0; i < 4; ++i)
            #pragma unroll
            for (int j = 0; j < 4; ++j) acc[i][j] += gv[i] * w4[j];
    }
    float a = 1.f / (1.f + expf(-skp_l[t]));
    #pragma unroll
    for (int i = 0; i < 4; ++i) {
        int r = row0 + ty + 16 * i;
        if (r >= NN) continue;
        float vals[4];
        float s1 = 0.f;
        #pragma unroll
        for (int j = 0; j < 4; ++j) {
            int c = tx + 16 * j;
            float o = a * (acc[i][j] + bas[c]) + (1.f - a) * xin[(size_t)r * CC + c];
            vals[j] = o;
            s1 += o;
        }
        s1 += __shfl_xor(s1, 1, 16);
        s1 += __shfl_xor(s1, 2, 16);
        s1 += __shfl_xor(s1, 4, 16);
        s1 += __shfl_xor(s1, 8, 16);
        float mean = s1 * (1.f / 64.f);
        float s2 = 0.f;
        #pragma unroll
        for (int j = 0; j < 4; ++j) {
            float dc = vals[j] - mean;
            s2 += dc * dc;
        }
        s2 += __shfl_xor(s2, 1, 16);
        s2 += __shfl_xor(s2, 2, 16);
        s2 += __shfl_xor(s2, 4, 16);
        s2 += __shfl_xor(s2, 8, 16);
        float inv = 1.f / sqrtf(s2 * (1.f / 64.f) + 1e-5f);
        #pragma unroll
        for (int j = 0; j < 4; ++j) {
            int c = tx + 16 * j;
            float y = (vals[j] - mean) * inv * lnws[c] + lnbs[c];
            xo[(size_t)r * CC + c] = geluf(y);
        }
    }
}

// ---------------- pooling scores: 64-row tile ------------------------------------------
__global__ __launch_bounds__(256) void scores_kernel(const float* __restrict__ X,
                                                     const float* __restrict__ Wfc, const float* __restrict__ bfc,
                                                     const float* __restrict__ Wsc, float* __restrict__ sc)
{
    int t = blockIdx.y;
    __shared__ float Xs[PR][CC + 1];
    __shared__ float Wfs[CC][33];
    __shared__ float bfs[32], wscs[32];
    int tid = threadIdx.x;
    int row0 = blockIdx.x * PR;
    const float* Xt = X + (size_t)t * NN * CC;
    for (int i = tid; i < CC * 32; i += 256) Wfs[i >> 5][i & 31] = Wfc[(size_t)t * CC * 32 + i];
    if (tid < 32) { bfs[tid] = bfc[t * 32 + tid]; wscs[tid] = Wsc[t * 32 + tid]; }
    for (int i = tid; i < PR * CC; i += 256) {
        int r = i >> 6, c = i & 63;
        int gr = row0 + r;
        Xs[r][c] = (gr < NN) ? Xt[(size_t)gr * CC + c] : 0.f;
    }
    __syncthreads();
    int tx = tid & 15, ty = tid >> 4;
    float acc[4][2];
    #pragma unroll
    for (int i = 0; i < 4; ++i) { acc[i][0] = 0.f; acc[i][1] = 0.f; }
    for (int k = 0; k < CC; ++k) {
        float w0 = Wfs[k][tx], w1 = Wfs[k][tx + 16];
        #pragma unroll
        for (int i = 0; i < 4; ++i) {
            float xv = Xs[ty + 16 * i][k];
            acc[i][0] += xv * w0;
            acc[i][1] += xv * w1;
        }
    }
    #pragma unroll
    for (int i = 0; i < 4; ++i) {
        float p = geluf(acc[i][0] + bfs[tx]) * wscs[tx]
                + geluf(acc[i][1] + bfs[tx + 16]) * wscs[tx + 16];
        p += __shfl_xor(p, 1, 16);
        p += __shfl_xor(p, 2, 16);
        p += __shfl_xor(p, 4, 16);
        p += __shfl_xor(p, 8, 16);
        int r = row0 + ty + 16 * i;
        if (tx == 0 && r < NN) sc[(size_t)t * NN + r] = p;
    }
}

// ---------------- top-8 (jax tie semantics: value desc, then lower index) ----------------
#define CHUNK 1250
__global__ __launch_bounds__(256) void topk1(const float* __restrict__ sc, float* __restrict__ candv,
                                             int* __restrict__ candi, int total)
{
    __shared__ float v[CHUNK];
    __shared__ float rv[256];
    __shared__ int ri[256];
    int tid = threadIdx.x;
    int base = blockIdx.x * CHUNK;
    for (int i = tid; i < CHUNK; i += 256) {
        int g = base + i;
        v[i] = (g < total) ? sc[g] : -INFINITY;
    }
    __syncthreads();
    for (int it = 0; it < 8; ++it) {
        float bv = v[tid]; int bi = tid;
        for (int i = tid + 256; i < CHUNK; i += 256) {
            float x = v[i];
            if (x > bv) { bv = x; bi = i; }
        }
        rv[tid] = bv; ri[tid] = bi;
        __syncthreads();
        for (int s2 = 128; s2 > 0; s2 >>= 1) {
            if (tid < s2) {
                float ov = rv[tid + s2]; int oi = ri[tid + s2];
                if (ov > rv[tid] || (ov == rv[tid] && oi < ri[tid])) { rv[tid] = ov; ri[tid] = oi; }
            }
            __syncthreads();
        }
        if (tid == 0) {
            candv[blockIdx.x * 8 + it] = rv[0];
            candi[blockIdx.x * 8 + it] = base + ri[0];
            v[ri[0]] = -INFINITY;
        }
        __syncthreads();
    }
}

#define NCAND 1920
__global__ __launch_bounds__(256) void topk2(const float* __restrict__ candv, const int* __restrict__ candi,
                                             float* __restrict__ topv, int* __restrict__ topi)
{
    __shared__ float v[NCAND];
    __shared__ int gi[NCAND];
    __shared__ float rv[256];
    __shared__ int ri[256];
    int tid = threadIdx.x;
    for (int i = tid; i < NCAND; i += 256) { v[i] = candv[i]; gi[i] = candi[i]; }
    __syncthreads();
    for (int it = 0; it < 8; ++it) {
        float bv = v[tid]; int bs = tid;
        for (int i = tid + 256; i < NCAND; i += 256) {
            float x = v[i];
            if (x > bv || (x == bv && gi[i] < gi[bs])) { bv = x; bs = i; }
        }
        rv[tid] = bv; ri[tid] = bs;
        __syncthreads();
        for (int s2 = 128; s2 > 0; s2 >>= 1) {
            if (tid < s2) {
                float ov = rv[tid + s2]; int os = ri[tid + s2];
                if (ov > rv[tid] || (ov == rv[tid] && gi[os] < gi[ri[tid]])) { rv[tid] = ov; ri[tid] = os; }
            }
            __syncthreads();
        }
        if (tid == 0) {
            topv[it] = rv[0];
            topi[it] = gi[ri[0]];
            v[ri[0]] = -INFINITY;
        }
        __syncthreads();
    }
}

// ---------------- final: recompute z for winners, pooled, MLP head ----------------
__global__ __launch_bounds__(256) void mlp_kernel(const float* __restrict__ X,
    const float* __restrict__ Wfc, const float* __restrict__ bfc,
    const float* __restrict__ topv, const int* __restrict__ topi,
    const float* __restrict__ W1, const float* __restrict__ b1,
    const float* __restrict__ W2, const float* __restrict__ b2,
    const float* __restrict__ W3, const float* __restrict__ b3,
    const float* __restrict__ W4, const float* __restrict__ b4,
    float* __restrict__ out)
{
    __shared__ float h0[256], h1[128], h2[64], h3[32];
    int tid = threadIdx.x;
    int wv = tid >> 6, lane = tid & 63;
    int j = lane & 31, half = lane >> 5;
    for (int w = wv; w < 8; w += 4) {
        int gidx = topi[w];
        float ts = topv[w];
        const float* xr = X + (size_t)gidx * 64;
        int t = gidx / NN;
        const float* Wf = Wfc + (size_t)t * CC * 32;
        float acc = 0.f;
        #pragma unroll
        for (int k2 = 0; k2 < 32; ++k2) {
            int k = half * 32 + k2;
            acc += xr[k] * Wf[k * 32 + j];
        }
        acc += __shfl_xor(acc, 32, 64);
        float z = geluf(acc + bfc[t * 32 + j]);
        if (half == 0) h0[w * 32 + j] = z * tanhf(ts);
    }
    __syncthreads();
    if (tid < 128) {
        float a = b1[tid];
        for (int k = 0; k < 256; ++k) a += h0[k] * W1[k * 128 + tid];
        h1[tid] = geluf(a);
    }
    __syncthreads();
    if (tid < 64) {
        float a = b2[tid];
        for (int k = 0; k < 128; ++k) a += h1[k] * W2[k * 64 + tid];
        h2[tid] = geluf(a);
    }
    __syncthreads();
    if (tid < 32) {
        float a = b3[tid];
        for (int k = 0; k < 64; ++k) a += h2[k] * W3[k * 32 + tid];
        h3[tid] = geluf(a);
    }
    __syncthreads();
    if (tid == 0) {
        float a = b4[0];
        for (int k = 0; k < 32; ++k) a += h3[k] * W4[k];
        if (isnan(a)) a = 0.f;
        else if (isinf(a)) a = (a > 0.f) ? FLT_MAX : -FLT_MAX;
        out[0] = a;
    }
}

extern "C" void kernel_launch(void* const* d_in, const int* in_sizes, int n_in,
                              void* d_out, int out_size, void* d_ws, size_t ws_size,
                              hipStream_t stream)
{
    (void)in_sizes; (void)n_in; (void)out_size;
    static const int h_r0[TT]   = {0, 2, 4};
    static const int h_nrel[TT] = {2, 2, 1};

    const float* xin0[TT] = {(const float*)d_in[0], (const float*)d_in[1], (const float*)d_in[2]};
    const int* ei[RR];
    for (int r = 0; r < RR; ++r) ei[r] = (const int*)d_in[3 + r];
    const float* Wk   = (const float*)d_in[8];
    const float* bk   = (const float*)d_in[9];
    const float* Wq   = (const float*)d_in[10];
    const float* bq   = (const float*)d_in[11];
    const float* Wv   = (const float*)d_in[12];
    const float* bv   = (const float*)d_in[13];
    const float* Wa   = (const float*)d_in[14];
    const float* ba   = (const float*)d_in[15];
    const float* skp  = (const float*)d_in[16];
    const float* lnw  = (const float*)d_in[17];
    const float* lnb  = (const float*)d_in[18];
    const float* a_rel = (const float*)d_in[19];
    const float* m_rel = (const float*)d_in[20];
    const float* p_rel = (const float*)d_in[21];
    const float* Wfc  = (const float*)d_in[22];
    const float* bfc  = (const float*)d_in[23];
    const float* Wsc  = (const float*)d_in[24];
    const float* W1 = (const float*)d_in[25]; const float* b1 = (const float*)d_in[26];
    const float* W2 = (const float*)d_in[27]; const float* b2 = (const float*)d_in[28];
    const float* W3 = (const float*)d_in[29]; const float* b3 = (const float*)d_in[30];
    const float* W4 = (const float*)d_in[31]; const float* b4 = (const float*)d_in[32];

    char* ws = (char*)d_ws;
    size_t off = 0;
    auto alloc = [&](size_t bytes) -> char* {
        char* p = ws + off;
        off = (off + bytes + 255) & ~(size_t)255;
        return p;
    };
    float* Xb   = (float*)alloc((size_t)TT * NN * CC * 4);   // 76.8 MB
    float* OUTb = (float*)alloc((size_t)TT * NN * CC * 4);   // 76.8 MB (pairs aliased here)
    float* KVb  = (float*)alloc((size_t)NN * 128 * 4);       // 51.2 MB  [node][K|V]
    float* WQE  = (float*)alloc((size_t)LL * RR * CC * CC * 4);  // 1.3 MB
    float* BQE  = (float*)alloc((size_t)LL * RR * CC * 4);
    int* indptr = (int*)alloc((size_t)RR * (NN + 1) * 4);    // 2.0 MB
    int* rowsrt = (int*)alloc((size_t)RR * EE * 4);          // 20.0 MB
    int* order  = (int*)alloc((size_t)RR * NN * 4);          // 2.0 MB degree-sorted node ids
    int* bcnt   = (int*)alloc((size_t)RR * NB * 4);
    int* bbase  = (int*)alloc((size_t)RR * (NB + 1) * 4);
    int* gcur   = (int*)alloc((size_t)RR * NB * 4);
    int* dbin   = (int*)alloc((size_t)RR * 256 * 4);
    float* scb  = (float*)alloc((size_t)TT * NN * 4);
    float* candv = (float*)alloc(240 * 8 * 4);
    int* candi   = (int*)alloc(240 * 8 * 4);
    float* topv  = (float*)alloc(64);
    int* topi    = (int*)alloc(64);
    unsigned* pairs = (unsigned*)OUTb;   // 20 MB alias; CSR build finishes before OUTb is used

    if (off > ws_size) {
        zero_out_kernel<<<1, 64, 0, stream>>>((float*)d_out);
        return;
    }

    // fold a_rel^T into the per-relation Q weights
    fuse_q<<<LL * RR, 256, 0, stream>>>(Wq, bq, a_rel, WQE, BQE);

    // ---- CSR build (bucketed two-phase counting sort), all 5 relations ----
    const int chunkGrid = (EE + 4095) / 4096;   // 245
    const int nGrid = (NN + 255) / 256;         // 391
    hipMemsetAsync(bcnt, 0, (size_t)RR * NB * 4, stream);
    bucket_hist<<<dim3(chunkGrid, RR), 256, 0, stream>>>(ei[0], ei[1], ei[2], ei[3], ei[4], bcnt);
    bucket_scan<<<RR, 256, 0, stream>>>(bcnt, bbase, gcur, indptr);
    bucket_partition<<<dim3(chunkGrid, RR), 256, 0, stream>>>(ei[0], ei[1], ei[2], ei[3], ei[4],
                                                              gcur, pairs);
    bucket_finalize<<<dim3(NB, RR), 256, 0, stream>>>(pairs, bbase, indptr, rowsrt);

    // ---- degree-sorted node order per relation (kills degree divergence in edge) ----
    hipMemsetAsync(dbin, 0, (size_t)RR * 256 * 4, stream);
    deg_hist<<<dim3(nGrid, RR), 256, 0, stream>>>(indptr, dbin);
    deg_scan<<<RR, 256, 0, stream>>>(dbin);
    deg_scatter<<<dim3(nGrid, RR), 256, 0, stream>>>(indptr, dbin, order);

    const int gproj = (NN + PR - 1) / PR;                   // 1563
    const int gedge = NN / 16;                              // 6250 (exact)
    const float* xcur[TT] = {xin0[0], xin0[1], xin0[2]};

    for (int l = 0; l < LL; ++l) {
        for (int s = 0; s < TT; ++s) {
            projKV_kernel<<<gproj, 256, 0, stream>>>(xcur[s],
                Wk + (size_t)(l * TT + s) * CC * CC, bk + (size_t)(l * TT + s) * CC,
                Wv + (size_t)(l * TT + s) * CC * CC, bv + (size_t)(l * TT + s) * CC,
                KVb, NN);
            int r0 = h_r0[s];
            int lr0 = l * RR + r0;
            edge_kernel<<<dim3(gedge, h_nrel[s]), 256, 0, stream>>>(
                indptr, rowsrt, order, xcur[0], xcur[1], xcur[2],
                WQE + (size_t)lr0 * CC * CC, BQE + (size_t)lr0 * CC,
                KVb, m_rel + (size_t)lr0 * HH * DD * DD, p_rel + (size_t)lr0 * HH,
                OUTb, r0);
        }
        post3_kernel<<<dim3(gproj, TT), 256, 0, stream>>>(xcur[0], xcur[1], xcur[2],
            OUTb, Xb,
            Wa + (size_t)l * TT * CC * CC, ba + (size_t)l * TT * CC,
            skp + l * TT,
            lnw + (size_t)l * TT * CC, lnb + (size_t)l * TT * CC);
        for (int t = 0; t < TT; ++t) xcur[t] = Xb + (size_t)t * NN * CC;
    }

    scores_kernel<<<dim3(gproj, TT), 256, 0, stream>>>(Xb, Wfc, bfc, Wsc, scb);
    topk1<<<240, 256, 0, stream>>>(scb, candv, candi, TT * NN);
    topk2<<<1, 256, 0, stream>>>(candv, candi, topv, topi);
    mlp_kernel<<<1, 256, 0, stream>>>(Xb, Wfc, bfc, topv, topi,
                                      W1, b1, W2, b2, W3, b3, W4, b4, (float*)d_out);
}

// Round 13
// 2928.786 us; speedup vs baseline: 1.3925x; 1.3925x over previous
//
#include <hip/hip_runtime.h>
#include <math.h>
#include <float.h>

#define NN 100000
#define EE 1000000
#define CC 64
#define HH 4
#define DD 16
#define LL 4
#define TT 3
#define RR 5
#define NB 196          // CSR buckets: 512 dsts each (196*512 >= NN)
#define PR 64           // row-tile for GEMM-family kernels

__device__ __constant__ int g_dst[RR]   = {0, 1, 0, 2, 0};
__device__ __constant__ int g_first[RR] = {1, 1, 0, 1, 0};

__device__ __forceinline__ float geluf(float x) {
    return 0.5f * x * (1.0f + erff(x * 0.7071067811865476f));
}

__global__ void zero_out_kernel(float* out) {
    if (threadIdx.x == 0 && blockIdx.x == 0) out[0] = 0.f;
}

__device__ __forceinline__ const int* sel_edge(int r, const int* p0, const int* p1,
                                               const int* p2, const int* p3, const int* p4) {
    return (r == 0) ? p0 : (r == 1) ? p1 : (r == 2) ? p2 : (r == 3) ? p3 : p4;
}

// ---------------- fuse Q weights with a_rel^T: WQE = Wq @ blockdiag(A^T) per (l,r) ------
__global__ __launch_bounds__(256) void fuse_q(
    const float* __restrict__ Wq, const float* __restrict__ bq,
    const float* __restrict__ a_rel,
    float* __restrict__ WQE, float* __restrict__ BQE)
{
    int lr = blockIdx.x;            // l*RR + r
    int l = lr / RR, r = lr % RR;
    int d = g_dst[r];
    const float* W  = Wq + (size_t)(l * TT + d) * CC * CC;
    const float* bb = bq + (size_t)(l * TT + d) * CC;
    const float* A  = a_rel + (size_t)lr * HH * DD * DD;
    float* Wo = WQE + (size_t)lr * CC * CC;
    float* bo = BQE + (size_t)lr * CC;

    for (int i = threadIdx.x; i < CC * CC; i += 256) {
        int c = i >> 6, j = i & 63, h = j >> 4, dout = j & 15;
        float acc = 0.f;
        #pragma unroll
        for (int e0 = 0; e0 < DD; ++e0)
            acc += W[c * CC + h * DD + e0] * A[(h * DD + dout) * DD + e0];
        Wo[i] = acc;
    }
    if (threadIdx.x < CC) {
        int j = threadIdx.x, h = j >> 4, dout = j & 15;
        float acc = 0.f;
        #pragma unroll
        for (int e0 = 0; e0 < DD; ++e0)
            acc += bb[h * DD + e0] * A[(h * DD + dout) * DD + e0];
        bo[j] = acc;
    }
}

// ================= CSR build: bucketed two-phase counting sort =================
__global__ __launch_bounds__(256) void bucket_hist(
    const int* __restrict__ p0, const int* __restrict__ p1, const int* __restrict__ p2,
    const int* __restrict__ p3, const int* __restrict__ p4, int* __restrict__ bcnt)
{
    int r = blockIdx.y;
    const int* col = sel_edge(r, p0, p1, p2, p3, p4) + EE;
    __shared__ int lh[256];
    int tid = threadIdx.x;
    lh[tid] = 0;
    __syncthreads();
    int base = blockIdx.x * 4096;
    for (int i = tid; i < 4096; i += 256) {
        int g = base + i;
        if (g < EE) atomicAdd(&lh[col[g] >> 9], 1);
    }
    __syncthreads();
    if (tid < NB && lh[tid]) atomicAdd(&bcnt[r * NB + tid], lh[tid]);
}

__global__ __launch_bounds__(256) void bucket_scan(
    const int* __restrict__ bcnt, int* __restrict__ bbase, int* __restrict__ gcur,
    int* __restrict__ indptr)
{
    int r = blockIdx.x;
    __shared__ int ls[256];
    int tid = threadIdx.x;
    ls[tid] = (tid < NB) ? bcnt[r * NB + tid] : 0;
    __syncthreads();
    for (int o = 1; o < 256; o <<= 1) {
        int v = (tid >= o) ? ls[tid - o] : 0;
        __syncthreads();
        ls[tid] += v;
        __syncthreads();
    }
    int ex = (tid == 0) ? 0 : ls[tid - 1];
    if (tid < NB) {
        bbase[r * (NB + 1) + tid] = ex;
        gcur[r * NB + tid] = ex;
    }
    if (tid == NB) bbase[r * (NB + 1) + NB] = ls[NB - 1];   // == EE
    if (tid == 0) indptr[(size_t)r * (NN + 1) + NN] = EE;
}

// P2: partition packed (col_local<<17 | row) into bucket-contiguous runs
__global__ __launch_bounds__(256) void bucket_partition(
    const int* __restrict__ p0, const int* __restrict__ p1, const int* __restrict__ p2,
    const int* __restrict__ p3, const int* __restrict__ p4,
    int* __restrict__ gcur, unsigned* __restrict__ pairs)
{
    int r = blockIdx.y;
    const int* ebase = sel_edge(r, p0, p1, p2, p3, p4);
    const int* colp = ebase + EE;
    __shared__ int2 stag[4096];
    __shared__ int lh[256], lofs[256], lcur[256], gpos[256];
    int tid = threadIdx.x;
    lh[tid] = 0;
    __syncthreads();
    int base = blockIdx.x * 4096;
    for (int i = tid; i < 4096; i += 256) {
        int g = base + i;
        if (g < EE) atomicAdd(&lh[colp[g] >> 9], 1);
    }
    __syncthreads();
    lofs[tid] = lh[tid];
    __syncthreads();
    for (int o = 1; o < 256; o <<= 1) {
        int v = (tid >= o) ? lofs[tid - o] : 0;
        __syncthreads();
        lofs[tid] += v;
        __syncthreads();
    }
    int ex = (tid == 0) ? 0 : lofs[tid - 1];
    __syncthreads();
    lofs[tid] = ex;
    lcur[tid] = ex;
    gpos[tid] = (lh[tid] > 0) ? atomicAdd(&gcur[r * NB + tid], lh[tid]) : 0;
    __syncthreads();
    for (int i = tid; i < 4096; i += 256) {
        int g = base + i;
        if (g < EE) {
            int c = colp[g];
            int b = c >> 9;
            int s = atomicAdd(&lcur[b], 1);
            stag[s] = make_int2(ebase[g], c);
        }
    }
    __syncthreads();
    int total = EE - base; if (total > 4096) total = 4096;
    for (int s = tid; s < total; s += 256) {
        int2 pr = stag[s];
        int b = pr.y >> 9;
        unsigned packed = ((unsigned)(pr.y & 511) << 17) | (unsigned)pr.x;
        pairs[(size_t)r * EE + gpos[b] + (s - lofs[b])] = packed;
    }
}

__global__ __launch_bounds__(256) void bucket_finalize(
    const unsigned* __restrict__ pairs, const int* __restrict__ bbase,
    int* __restrict__ indptr, int* __restrict__ rowsrt)
{
    int r = blockIdx.y, b = blockIdx.x;
    int beg = bbase[r * (NB + 1) + b], end = bbase[r * (NB + 1) + b + 1];
    int d0 = b << 9;
    int nd = NN - d0; if (nd > 512) nd = 512;
    __shared__ int cnt[512];
    __shared__ int exc[512];
    __shared__ int ls[256];
    int tid = threadIdx.x;
    cnt[tid] = 0; cnt[tid + 256] = 0;
    __syncthreads();
    const unsigned* pp = pairs + (size_t)r * EE;
    for (int e = beg + tid; e < end; e += 256)
        atomicAdd(&cnt[pp[e] >> 17], 1);
    __syncthreads();
    int a0 = cnt[2 * tid], a1 = cnt[2 * tid + 1];
    ls[tid] = a0 + a1;
    __syncthreads();
    for (int o = 1; o < 256; o <<= 1) {
        int v = (tid >= o) ? ls[tid - o] : 0;
        __syncthreads();
        ls[tid] += v;
        __syncthreads();
    }
    int ex2 = (tid == 0) ? 0 : ls[tid - 1];
    exc[2 * tid] = ex2;
    exc[2 * tid + 1] = ex2 + a0;
    __syncthreads();
    for (int i = tid; i < nd; i += 256)
        indptr[(size_t)r * (NN + 1) + d0 + i] = beg + exc[i];
    cnt[2 * tid] = exc[2 * tid];
    cnt[2 * tid + 1] = exc[2 * tid + 1];
    __syncthreads();
    for (int e = beg + tid; e < end; e += 256) {
        unsigned pr = pp[e];
        int p = atomicAdd(&cnt[pr >> 17], 1);
        rowsrt[(size_t)r * EE + beg + p] = (int)(pr & 0x1FFFFu);
    }
}

// ====== degree-sorted node order — contention-free (block-local hist + range reserve) ===
__global__ __launch_bounds__(256) void deg_hist(const int* __restrict__ indptr,
                                                int* __restrict__ dbin)
{
    int r = blockIdx.y;
    __shared__ int lh[256];
    int tid = threadIdx.x;
    lh[tid] = 0;
    __syncthreads();
    int i = blockIdx.x * 256 + tid;
    if (i < NN) {
        const int* ip = indptr + (size_t)r * (NN + 1);
        int deg = ip[i + 1] - ip[i];
        if (deg > 255) deg = 255;
        atomicAdd(&lh[deg], 1);             // LDS atomic: fast
    }
    __syncthreads();
    if (lh[tid]) atomicAdd(&dbin[r * 256 + tid], lh[tid]);   // 1 global atomic / bin / block
}

__global__ __launch_bounds__(256) void deg_scan(int* __restrict__ dbin)
{
    int r = blockIdx.x;
    __shared__ int ls[256];
    int tid = threadIdx.x;
    ls[tid] = dbin[r * 256 + tid];
    __syncthreads();
    for (int o = 1; o < 256; o <<= 1) {
        int v = (tid >= o) ? ls[tid - o] : 0;
        __syncthreads();
        ls[tid] += v;
        __syncthreads();
    }
    dbin[r * 256 + tid] = (tid == 0) ? 0 : ls[tid - 1];   // exclusive -> cursor
}

__global__ __launch_bounds__(256) void deg_scatter(const int* __restrict__ indptr,
                                                   int* __restrict__ dbin,
                                                   int* __restrict__ order)
{
    int r = blockIdx.y;
    __shared__ int lh[256], gpos[256], lcur[256];
    int tid = threadIdx.x;
    lh[tid] = 0;
    __syncthreads();
    int i = blockIdx.x * 256 + tid;
    int deg = -1;
    if (i < NN) {
        const int* ip = indptr + (size_t)r * (NN + 1);
        deg = ip[i + 1] - ip[i];
        if (deg > 255) deg = 255;
        atomicAdd(&lh[deg], 1);
    }
    __syncthreads();
    gpos[tid] = (lh[tid] > 0) ? atomicAdd(&dbin[r * 256 + tid], lh[tid]) : 0;
    lcur[tid] = 0;
    __syncthreads();
    if (i < NN) {
        int p = atomicAdd(&lcur[deg], 1);   // LDS atomic
        order[(size_t)r * NN + gpos[deg] + p] = i;
    }
}

// ---------------- fused K+V projection (per TYPE) -> KV[node][0:64]=K, [64:128]=V ------
__global__ __launch_bounds__(256) void projKV_kernel(
    const float* __restrict__ X,
    const float* __restrict__ WK, const float* __restrict__ BK,
    const float* __restrict__ WV, const float* __restrict__ BV,
    float* __restrict__ KV, int nrows)
{
    __shared__ float Xs[PR][CC + 1];
    __shared__ float WKs[CC][CC];
    __shared__ float WVs[CC][CC];
    __shared__ float bks[CC], bvs[CC];
    int tid = threadIdx.x;
    int row0 = blockIdx.x * PR;
    for (int i = tid; i < CC * CC; i += 256) {
        WKs[i >> 6][i & 63] = WK[i];
        WVs[i >> 6][i & 63] = WV[i];
    }
    if (tid < CC) { bks[tid] = BK[tid]; bvs[tid] = BV[tid]; }
    for (int i = tid; i < PR * CC; i += 256) {
        int r = i >> 6, c = i & 63;
        int gr = row0 + r;
        Xs[r][c] = (gr < nrows) ? X[(size_t)gr * CC + c] : 0.f;
    }
    __syncthreads();
    int tx = tid & 15, ty = tid >> 4;
    float aK[4][4], aV[4][4];
    #pragma unroll
    for (int i = 0; i < 4; ++i)
        #pragma unroll
        for (int j = 0; j < 4; ++j) { aK[i][j] = 0.f; aV[i][j] = 0.f; }
    for (int k = 0; k < CC; ++k) {
        float xv[4], wk4[4], wv4[4];
        #pragma unroll
        for (int i = 0; i < 4; ++i) xv[i] = Xs[ty + 16 * i][k];
        #pragma unroll
        for (int j = 0; j < 4; ++j) { wk4[j] = WKs[k][tx + 16 * j]; wv4[j] = WVs[k][tx + 16 * j]; }
        #pragma unroll
        for (int i = 0; i < 4; ++i)
            #pragma unroll
            for (int j = 0; j < 4; ++j) {
                aK[i][j] += xv[i] * wk4[j];
                aV[i][j] += xv[i] * wv4[j];
            }
    }
    #pragma unroll
    for (int i = 0; i < 4; ++i) {
        int r = row0 + ty + 16 * i;
        if (r < nrows) {
            #pragma unroll
            for (int j = 0; j < 4; ++j) {
                int c = tx + 16 * j;
                KV[(size_t)r * 128 + c]      = aK[i][j] + bks[c];
                KV[(size_t)r * 128 + 64 + c] = aV[i][j] + bvs[c];
            }
        }
    }
}

// ---------------- edge pass: degree-sorted nodes; 4 dst nodes/wave ---------------------
__global__ __launch_bounds__(256) void edge_kernel(
    const int* __restrict__ indptr_all, const int* __restrict__ rows_all,
    const int* __restrict__ order_all,
    const float* __restrict__ x0, const float* __restrict__ x1, const float* __restrict__ x2,
    const float* __restrict__ WQE_l, const float* __restrict__ BQE_l,
    const float* __restrict__ kv, const float* __restrict__ Mrel_l,
    const float* __restrict__ prel_l,
    float* __restrict__ outb, int r0)
{
    int ri = blockIdx.y;
    int r = r0 + ri;
    int d = g_dst[r];
    const float* xd = (d == 0) ? x0 : (d == 1) ? x1 : x2;
    const int* indptr = indptr_all + (size_t)r * (NN + 1);
    const int* rows = rows_all + (size_t)r * EE;
    const int* order = order_all + (size_t)r * NN;
    const float* Wq = WQE_l + (size_t)ri * CC * CC;
    const float* bqp = BQE_l + (size_t)ri * CC;
    const float* Mrel = Mrel_l + (size_t)ri * HH * DD * DD;
    const float* prel = prel_l + (size_t)ri * HH;
    float* outp = outb + (size_t)d * NN * CC;
    int accum = 1 - g_first[r];

    __shared__ float4 Wq4s[CC][16];    // 16 KB
    __shared__ float  xs[16][CC + 4];  // padded: groups hit distinct banks
    __shared__ float4 bq4s[16];
    int tid = threadIdx.x;
    const float4* Wq4 = (const float4*)Wq;
    for (int i = tid; i < CC * 16; i += 256)
        Wq4s[i >> 4][i & 15] = Wq4[i];
    if (tid < 16) bq4s[tid] = ((const float4*)bqp)[tid];

    int g = tid >> 4;                 // node slot 0..15
    int gl = tid & 15;                // lane in group: channels 4gl..4gl+3
    int node = order[blockIdx.x * 16 + g];   // degree-sorted permutation
    {
        float4 xv4 = ((const float4*)xd)[(size_t)node * 16 + gl];
        ((float4*)&xs[g][0])[gl] = xv4;
    }
    __syncthreads();

    int h = gl >> 2;
    float ps = prel[h] * (0.25f * 1.4426950408889634f);

    float4 q4 = bq4s[gl];
    #pragma unroll 8
    for (int k = 0; k < CC; ++k) {
        float xk = xs[g][k];
        float4 w = Wq4s[k][gl];
        q4.x += xk * w.x; q4.y += xk * w.y; q4.z += xk * w.z; q4.w += xk * w.w;
    }

    int beg = indptr[node], end = indptr[node + 1];
    float m = -INFINITY, ss = 0.f;
    float4 o4 = make_float4(0.f, 0.f, 0.f, 0.f);
    const float4* kv4 = (const float4*)kv;
    for (int e = beg; e < end; ++e) {
        int rr = rows[e];
        const float4* kp = kv4 + (size_t)rr * 32;
        float4 k4 = kp[gl];
        float4 v4 = kp[16 + gl];
        float p = q4.x * k4.x + q4.y * k4.y + q4.z * k4.z + q4.w * k4.w;
        p += __shfl_xor(p, 1, 4);
        p += __shfl_xor(p, 2, 4);
        float al = p * ps;
        float nm = fmaxf(m, al);
        float sc = exp2f(m - nm);
        float ei = exp2f(al - nm);
        ss = ss * sc + ei;
        o4.x = o4.x * sc + ei * v4.x;
        o4.y = o4.y * sc + ei * v4.y;
        o4.z = o4.z * sc + ei * v4.z;
        o4.w = o4.w * sc + ei * v4.w;
        m = nm;
    }
    float inv = 1.f / (ss + 1e-16f);
    float4 res = make_float4(o4.x * inv, o4.y * inv, o4.z * inv, o4.w * inv);

    // out[h,e] = sum_d res[h,d] * M[h][d][e]  (M from global: 4 KB, L2-hot)
    const float4* Ms4 = (const float4*)Mrel;
    float4 out4 = make_float4(0.f, 0.f, 0.f, 0.f);
    int e4 = gl & 3;
    #pragma unroll
    for (int sl = 0; sl < 4; ++sl) {
        int src = (gl & 12) + sl;
        float a0 = __shfl(res.x, src, 16);
        float a1 = __shfl(res.y, src, 16);
        float a2 = __shfl(res.z, src, 16);
        float a3 = __shfl(res.w, src, 16);
        float4 m0 = Ms4[(h * DD + sl * 4 + 0) * 4 + e4];
        float4 m1 = Ms4[(h * DD + sl * 4 + 1) * 4 + e4];
        float4 m2 = Ms4[(h * DD + sl * 4 + 2) * 4 + e4];
        float4 m3 = Ms4[(h * DD + sl * 4 + 3) * 4 + e4];
        out4.x += a0 * m0.x + a1 * m1.x + a2 * m2.x + a3 * m3.x;
        out4.y += a0 * m0.y + a1 * m1.y + a2 * m2.y + a3 * m3.y;
        out4.z += a0 * m0.z + a1 * m1.z + a2 * m2.z + a3 * m3.z;
        out4.w += a0 * m0.w + a1 * m1.w + a2 * m2.w + a3 * m3.w;
    }

    float4* op = (float4*)outp + (size_t)node * 16;
    if (accum) {
        float4 old = op[gl];
        out4.x += old.x; out4.y += old.y; out4.z += old.z; out4.w += old.w;
    }
    op[gl] = out4;
}

// ---------------- post: 64-row GEMM tile + fused skip/LN/gelu --------------------------
__global__ __launch_bounds__(256) void post3_kernel(
    const float* __restrict__ x0, const float* __restrict__ x1, const float* __restrict__ x2,
    const float* __restrict__ outc, float* __restrict__ xout,
    const float* __restrict__ Wa_l, const float* __restrict__ ba_l,
    const float* __restrict__ skp_l,
    const float* __restrict__ lnw_l, const float* __restrict__ lnb_l)
{
    int t = blockIdx.y;
    const float* xin = (t == 0) ? x0 : (t == 1) ? x1 : x2;
    const float* Wa = Wa_l + (size_t)t * CC * CC;
    const float* ba = ba_l + (size_t)t * CC;
    const float* lnw = lnw_l + (size_t)t * CC;
    const float* lnb = lnb_l + (size_t)t * CC;
    const float* oc = outc + (size_t)t * NN * CC;
    float* xo = xout + (size_t)t * NN * CC;

    __shared__ float Gs[PR][CC + 1];
    __shared__ float Was[CC][CC];
    __shared__ float bas[CC], lnws[CC], lnbs[CC];
    int tid = threadIdx.x;
    int row0 = blockIdx.x * PR;
    for (int i = tid; i < CC * CC; i += 256) Was[i >> 6][i & 63] = Wa[i];
    if (tid < CC) { bas[tid] = ba[tid]; lnws[tid] = lnw[tid]; lnbs[tid] = lnb[tid]; }
    for (int i = tid; i < PR * CC; i += 256) {
        int r = i >> 6, c = i & 63;
        int gr = row0 + r;
        Gs[r][c] = (gr < NN) ? geluf(oc[(size_t)gr * CC + c]) : 0.f;
    }
    __syncthreads();
    int tx = tid & 15, ty = tid >> 4;
    float acc[4][4];
    #pragma unroll
    for (int i = 0; i < 4; ++i)
        #pragma unroll
        for (int j = 0; j < 4; ++j) acc[i][j] = 0.f;
    for (int k = 0; k < CC; ++k) {
        float gv[4], w4[4];
        #pragma unroll
        for (int i = 0; i < 4; ++i) gv[i] = Gs[ty + 16 * i][k];
        #pragma unroll
        for (int j = 0; j < 4; ++j) w4[j] = Was[k][tx + 16 * j];
        #pragma unroll
        for (int i = 0; i < 4; ++i)
            #pragma unroll
            for (int j = 0; j < 4; ++j) acc[i][j] += gv[i] * w4[j];
    }
    float a = 1.f / (1.f + expf(-skp_l[t]));
    #pragma unroll
    for (int i = 0; i < 4; ++i) {
        int r = row0 + ty + 16 * i;
        if (r >= NN) continue;
        float vals[4];
        float s1 = 0.f;
        #pragma unroll
        for (int j = 0; j < 4; ++j) {
            int c = tx + 16 * j;
            float o = a * (acc[i][j] + bas[c]) + (1.f - a) * xin[(size_t)r * CC + c];
            vals[j] = o;
            s1 += o;
        }
        s1 += __shfl_xor(s1, 1, 16);
        s1 += __shfl_xor(s1, 2, 16);
        s1 += __shfl_xor(s1, 4, 16);
        s1 += __shfl_xor(s1, 8, 16);
        float mean = s1 * (1.f / 64.f);
        float s2 = 0.f;
        #pragma unroll
        for (int j = 0; j < 4; ++j) {
            float dc = vals[j] - mean;
            s2 += dc * dc;
        }
        s2 += __shfl_xor(s2, 1, 16);
        s2 += __shfl_xor(s2, 2, 16);
        s2 += __shfl_xor(s2, 4, 16);
        s2 += __shfl_xor(s2, 8, 16);
        float inv = 1.f / sqrtf(s2 * (1.f / 64.f) + 1e-5f);
        #pragma unroll
        for (int j = 0; j < 4; ++j) {
            int c = tx + 16 * j;
            float y = (vals[j] - mean) * inv * lnws[c] + lnbs[c];
            xo[(size_t)r * CC + c] = geluf(y);
        }
    }
}

// ---------------- pooling scores: 64-row tile ------------------------------------------
__global__ __launch_bounds__(256) void scores_kernel(const float* __restrict__ X,
                                                     const float* __restrict__ Wfc, const float* __restrict__ bfc,
                                                     const float* __restrict__ Wsc, float* __restrict__ sc)
{
    int t = blockIdx.y;
    __shared__ float Xs[PR][CC + 1];
    __shared__ float Wfs[CC][33];
    __shared__ float bfs[32], wscs[32];
    int tid = threadIdx.x;
    int row0 = blockIdx.x * PR;
    const float* Xt = X + (size_t)t * NN * CC;
    for (int i = tid; i < CC * 32; i += 256) Wfs[i >> 5][i & 31] = Wfc[(size_t)t * CC * 32 + i];
    if (tid < 32) { bfs[tid] = bfc[t * 32 + tid]; wscs[tid] = Wsc[t * 32 + tid]; }
    for (int i = tid; i < PR * CC; i += 256) {
        int r = i >> 6, c = i & 63;
        int gr = row0 + r;
        Xs[r][c] = (gr < NN) ? Xt[(size_t)gr * CC + c] : 0.f;
    }
    __syncthreads();
    int tx = tid & 15, ty = tid >> 4;
    float acc[4][2];
    #pragma unroll
    for (int i = 0; i < 4; ++i) { acc[i][0] = 0.f; acc[i][1] = 0.f; }
    for (int k = 0; k < CC; ++k) {
        float w0 = Wfs[k][tx], w1 = Wfs[k][tx + 16];
        #pragma unroll
        for (int i = 0; i < 4; ++i) {
            float xv = Xs[ty + 16 * i][k];
            acc[i][0] += xv * w0;
            acc[i][1] += xv * w1;
        }
    }
    #pragma unroll
    for (int i = 0; i < 4; ++i) {
        float p = geluf(acc[i][0] + bfs[tx]) * wscs[tx]
                + geluf(acc[i][1] + bfs[tx + 16]) * wscs[tx + 16];
        p += __shfl_xor(p, 1, 16);
        p += __shfl_xor(p, 2, 16);
        p += __shfl_xor(p, 4, 16);
        p += __shfl_xor(p, 8, 16);
        int r = row0 + ty + 16 * i;
        if (tx == 0 && r < NN) sc[(size_t)t * NN + r] = p;
    }
}

// ---------------- top-8 (jax tie semantics: value desc, then lower index) ----------------
#define CHUNK 1250
__global__ __launch_bounds__(256) void topk1(const float* __restrict__ sc, float* __restrict__ candv,
                                             int* __restrict__ candi, int total)
{
    __shared__ float v[CHUNK];
    __shared__ float rv[256];
    __shared__ int ri[256];
    int tid = threadIdx.x;
    int base = blockIdx.x * CHUNK;
    for (int i = tid; i < CHUNK; i += 256) {
        int g = base + i;
        v[i] = (g < total) ? sc[g] : -INFINITY;
    }
    __syncthreads();
    for (int it = 0; it < 8; ++it) {
        float bv = v[tid]; int bi = tid;
        for (int i = tid + 256; i < CHUNK; i += 256) {
            float x = v[i];
            if (x > bv) { bv = x; bi = i; }
        }
        rv[tid] = bv; ri[tid] = bi;
        __syncthreads();
        for (int s2 = 128; s2 > 0; s2 >>= 1) {
            if (tid < s2) {
                float ov = rv[tid + s2]; int oi = ri[tid + s2];
                if (ov > rv[tid] || (ov == rv[tid] && oi < ri[tid])) { rv[tid] = ov; ri[tid] = oi; }
            }
            __syncthreads();
        }
        if (tid == 0) {
            candv[blockIdx.x * 8 + it] = rv[0];
            candi[blockIdx.x * 8 + it] = base + ri[0];
            v[ri[0]] = -INFINITY;
        }
        __syncthreads();
    }
}

#define NCAND 1920
__global__ __launch_bounds__(256) void topk2(const float* __restrict__ candv, const int* __restrict__ candi,
                                             float* __restrict__ topv, int* __restrict__ topi)
{
    __shared__ float v[NCAND];
    __shared__ int gi[NCAND];
    __shared__ float rv[256];
    __shared__ int ri[256];
    int tid = threadIdx.x;
    for (int i = tid; i < NCAND; i += 256) { v[i] = candv[i]; gi[i] = candi[i]; }
    __syncthreads();
    for (int it = 0; it < 8; ++it) {
        float bv = v[tid]; int bs = tid;
        for (int i = tid + 256; i < NCAND; i += 256) {
            float x = v[i];
            if (x > bv || (x == bv && gi[i] < gi[bs])) { bv = x; bs = i; }
        }
        rv[tid] = bv; ri[tid] = bs;
        __syncthreads();
        for (int s2 = 128; s2 > 0; s2 >>= 1) {
            if (tid < s2) {
                float ov = rv[tid + s2]; int os = ri[tid + s2];
                if (ov > rv[tid] || (ov == rv[tid] && gi[os] < gi[ri[tid]])) { rv[tid] = ov; ri[tid] = os; }
            }
            __syncthreads();
        }
        if (tid == 0) {
            topv[it] = rv[0];
            topi[it] = gi[ri[0]];
            v[ri[0]] = -INFINITY;
        }
        __syncthreads();
    }
}

// ---------------- final: recompute z for winners, pooled, MLP head ----------------
__global__ __launch_bounds__(256) void mlp_kernel(const float* __restrict__ X,
    const float* __restrict__ Wfc, const float* __restrict__ bfc,
    const float* __restrict__ topv, const int* __restrict__ topi,
    const float* __restrict__ W1, const float* __restrict__ b1,
    const float* __restrict__ W2, const float* __restrict__ b2,
    const float* __restrict__ W3, const float* __restrict__ b3,
    const float* __restrict__ W4, const float* __restrict__ b4,
    float* __restrict__ out)
{
    __shared__ float h0[256], h1[128], h2[64], h3[32];
    int tid = threadIdx.x;
    int wv = tid >> 6, lane = tid & 63;
    int j = lane & 31, half = lane >> 5;
    for (int w = wv; w < 8; w += 4) {
        int gidx = topi[w];
        float ts = topv[w];
        const float* xr = X + (size_t)gidx * 64;
        int t = gidx / NN;
        const float* Wf = Wfc + (size_t)t * CC * 32;
        float acc = 0.f;
        #pragma unroll
        for (int k2 = 0; k2 < 32; ++k2) {
            int k = half * 32 + k2;
            acc += xr[k] * Wf[k * 32 + j];
        }
        acc += __shfl_xor(acc, 32, 64);
        float z = geluf(acc + bfc[t * 32 + j]);
        if (half == 0) h0[w * 32 + j] = z * tanhf(ts);
    }
    __syncthreads();
    if (tid < 128) {
        float a = b1[tid];
        for (int k = 0; k < 256; ++k) a += h0[k] * W1[k * 128 + tid];
        h1[tid] = geluf(a);
    }
    __syncthreads();
    if (tid < 64) {
        float a = b2[tid];
        for (int k = 0; k < 128; ++k) a += h1[k] * W2[k * 64 + tid];
        h2[tid] = geluf(a);
    }
    __syncthreads();
    if (tid < 32) {
        float a = b3[tid];
        for (int k = 0; k < 64; ++k) a += h2[k] * W3[k * 32 + tid];
        h3[tid] = geluf(a);
    }
    __syncthreads();
    if (tid == 0) {
        float a = b4[0];
        for (int k = 0; k < 32; ++k) a += h3[k] * W4[k];
        if (isnan(a)) a = 0.f;
        else if (isinf(a)) a = (a > 0.f) ? FLT_MAX : -FLT_MAX;
        out[0] = a;
    }
}

extern "C" void kernel_launch(void* const* d_in, const int* in_sizes, int n_in,
                              void* d_out, int out_size, void* d_ws, size_t ws_size,
                              hipStream_t stream)
{
    (void)in_sizes; (void)n_in; (void)out_size;
    static const int h_r0[TT]   = {0, 2, 4};
    static const int h_nrel[TT] = {2, 2, 1};

    const float* xin0[TT] = {(const float*)d_in[0], (const float*)d_in[1], (const float*)d_in[2]};
    const int* ei[RR];
    for (int r = 0; r < RR; ++r) ei[r] = (const int*)d_in[3 + r];
    const float* Wk   = (const float*)d_in[8];
    const float* bk   = (const float*)d_in[9];
    const float* Wq   = (const float*)d_in[10];
    const float* bq   = (const float*)d_in[11];
    const float* Wv   = (const float*)d_in[12];
    const float* bv   = (const float*)d_in[13];
    const float* Wa   = (const float*)d_in[14];
    const float* ba   = (const float*)d_in[15];
    const float* skp  = (const float*)d_in[16];
    const float* lnw  = (const float*)d_in[17];
    const float* lnb  = (const float*)d_in[18];
    const float* a_rel = (const float*)d_in[19];
    const float* m_rel = (const float*)d_in[20];
    const float* p_rel = (const float*)d_in[21];
    const float* Wfc  = (const float*)d_in[22];
    const float* bfc  = (const float*)d_in[23];
    const float* Wsc  = (const float*)d_in[24];
    const float* W1 = (const float*)d_in[25]; const float* b1 = (const float*)d_in[26];
    const float* W2 = (const float*)d_in[27]; const float* b2 = (const float*)d_in[28];
    const float* W3 = (const float*)d_in[29]; const float* b3 = (const float*)d_in[30];
    const float* W4 = (const float*)d_in[31]; const float* b4 = (const float*)d_in[32];

    char* ws = (char*)d_ws;
    size_t off = 0;
    auto alloc = [&](size_t bytes) -> char* {
        char* p = ws + off;
        off = (off + bytes + 255) & ~(size_t)255;
        return p;
    };
    float* Xb   = (float*)alloc((size_t)TT * NN * CC * 4);   // 76.8 MB
    float* OUTb = (float*)alloc((size_t)TT * NN * CC * 4);   // 76.8 MB (pairs aliased here)
    float* KVb  = (float*)alloc((size_t)NN * 128 * 4);       // 51.2 MB  [node][K|V]
    float* WQE  = (float*)alloc((size_t)LL * RR * CC * CC * 4);  // 1.3 MB
    float* BQE  = (float*)alloc((size_t)LL * RR * CC * 4);
    int* indptr = (int*)alloc((size_t)RR * (NN + 1) * 4);    // 2.0 MB
    int* rowsrt = (int*)alloc((size_t)RR * EE * 4);          // 20.0 MB
    int* order  = (int*)alloc((size_t)RR * NN * 4);          // 2.0 MB degree-sorted node ids
    int* bcnt   = (int*)alloc((size_t)RR * NB * 4);
    int* bbase  = (int*)alloc((size_t)RR * (NB + 1) * 4);
    int* gcur   = (int*)alloc((size_t)RR * NB * 4);
    int* dbin   = (int*)alloc((size_t)RR * 256 * 4);
    float* scb  = (float*)alloc((size_t)TT * NN * 4);
    float* candv = (float*)alloc(240 * 8 * 4);
    int* candi   = (int*)alloc(240 * 8 * 4);
    float* topv  = (float*)alloc(64);
    int* topi    = (int*)alloc(64);
    unsigned* pairs = (unsigned*)OUTb;   // 20 MB alias; CSR build finishes before OUTb is used

    if (off > ws_size) {
        zero_out_kernel<<<1, 64, 0, stream>>>((float*)d_out);
        return;
    }

    // fold a_rel^T into the per-relation Q weights
    fuse_q<<<LL * RR, 256, 0, stream>>>(Wq, bq, a_rel, WQE, BQE);

    // ---- CSR build (bucketed two-phase counting sort), all 5 relations ----
    const int chunkGrid = (EE + 4095) / 4096;   // 245
    const int nGrid = (NN + 255) / 256;         // 391
    hipMemsetAsync(bcnt, 0, (size_t)RR * NB * 4, stream);
    bucket_hist<<<dim3(chunkGrid, RR), 256, 0, stream>>>(ei[0], ei[1], ei[2], ei[3], ei[4], bcnt);
    bucket_scan<<<RR, 256, 0, stream>>>(bcnt, bbase, gcur, indptr);
    bucket_partition<<<dim3(chunkGrid, RR), 256, 0, stream>>>(ei[0], ei[1], ei[2], ei[3], ei[4],
                                                              gcur, pairs);
    bucket_finalize<<<dim3(NB, RR), 256, 0, stream>>>(pairs, bbase, indptr, rowsrt);

    // ---- degree-sorted node order per relation (contention-free two-phase sort) ----
    hipMemsetAsync(dbin, 0, (size_t)RR * 256 * 4, stream);
    deg_hist<<<dim3(nGrid, RR), 256, 0, stream>>>(indptr, dbin);
    deg_scan<<<RR, 256, 0, stream>>>(dbin);
    deg_scatter<<<dim3(nGrid, RR), 256, 0, stream>>>(indptr, dbin, order);

    const int gproj = (NN + PR - 1) / PR;                   // 1563
    const int gedge = NN / 16;                              // 6250 (exact)
    const float* xcur[TT] = {xin0[0], xin0[1], xin0[2]};

    for (int l = 0; l < LL; ++l) {
        for (int s = 0; s < TT; ++s) {
            projKV_kernel<<<gproj, 256, 0, stream>>>(xcur[s],
                Wk + (size_t)(l * TT + s) * CC * CC, bk + (size_t)(l * TT + s) * CC,
                Wv + (size_t)(l * TT + s) * CC * CC, bv + (size_t)(l * TT + s) * CC,
                KVb, NN);
            int r0 = h_r0[s];
            int lr0 = l * RR + r0;
            edge_kernel<<<dim3(gedge, h_nrel[s]), 256, 0, stream>>>(
                indptr, rowsrt, order, xcur[0], xcur[1], xcur[2],
                WQE + (size_t)lr0 * CC * CC, BQE + (size_t)lr0 * CC,
                KVb, m_rel + (size_t)lr0 * HH * DD * DD, p_rel + (size_t)lr0 * HH,
                OUTb, r0);
        }
        post3_kernel<<<dim3(gproj, TT), 256, 0, stream>>>(xcur[0], xcur[1], xcur[2],
            OUTb, Xb,
            Wa + (size_t)l * TT * CC * CC, ba + (size_t)l * TT * CC,
            skp + l * TT,
            lnw + (size_t)l * TT * CC, lnb + (size_t)l * TT * CC);
        for (int t = 0; t < TT; ++t) xcur[t] = Xb + (size_t)t * NN * CC;
    }

    scores_kernel<<<dim3(gproj, TT), 256, 0, stream>>>(Xb, Wfc, bfc, Wsc, scb);
    topk1<<<240, 256, 0, stream>>>(scb, candv, candi, TT * NN);
    topk2<<<1, 256, 0, stream>>>(candv, candi, topv, topi);
    mlp_kernel<<<1, 256, 0, stream>>>(Xb, Wfc, bfc, topv, topi,
                                      W1, b1, W2, b2, W3, b3, W4, b4, (float*)d_out);
}

// Round 14
// 2813.946 us; speedup vs baseline: 1.4494x; 1.0408x over previous
//
#include <hip/hip_runtime.h>
#include <math.h>
#include <float.h>

#define NN 100000
#define EE 1000000
#define CC 64
#define HH 4
#define DD 16
#define LL 4
#define TT 3
#define RR 5
#define NB 196          // CSR buckets: 512 dsts each (196*512 >= NN)
#define PR 64           // row-tile for GEMM-family kernels

__device__ __constant__ int g_dst[RR]   = {0, 1, 0, 2, 0};
__device__ __constant__ int g_first[RR] = {1, 1, 0, 1, 0};

__device__ __forceinline__ float geluf(float x) {
    return 0.5f * x * (1.0f + erff(x * 0.7071067811865476f));
}

__global__ void zero_out_kernel(float* out) {
    if (threadIdx.x == 0 && blockIdx.x == 0) out[0] = 0.f;
}

__device__ __forceinline__ const int* sel_edge(int r, const int* p0, const int* p1,
                                               const int* p2, const int* p3, const int* p4) {
    return (r == 0) ? p0 : (r == 1) ? p1 : (r == 2) ? p2 : (r == 3) ? p3 : p4;
}

// ---------------- fuse Q weights with a_rel^T: WQE = Wq @ blockdiag(A^T) per (l,r) ------
__global__ __launch_bounds__(256) void fuse_q(
    const float* __restrict__ Wq, const float* __restrict__ bq,
    const float* __restrict__ a_rel,
    float* __restrict__ WQE, float* __restrict__ BQE)
{
    int lr = blockIdx.x;            // l*RR + r
    int l = lr / RR, r = lr % RR;
    int d = g_dst[r];
    const float* W  = Wq + (size_t)(l * TT + d) * CC * CC;
    const float* bb = bq + (size_t)(l * TT + d) * CC;
    const float* A  = a_rel + (size_t)lr * HH * DD * DD;
    float* Wo = WQE + (size_t)lr * CC * CC;
    float* bo = BQE + (size_t)lr * CC;

    for (int i = threadIdx.x; i < CC * CC; i += 256) {
        int c = i >> 6, j = i & 63, h = j >> 4, dout = j & 15;
        float acc = 0.f;
        #pragma unroll
        for (int e0 = 0; e0 < DD; ++e0)
            acc += W[c * CC + h * DD + e0] * A[(h * DD + dout) * DD + e0];
        Wo[i] = acc;
    }
    if (threadIdx.x < CC) {
        int j = threadIdx.x, h = j >> 4, dout = j & 15;
        float acc = 0.f;
        #pragma unroll
        for (int e0 = 0; e0 < DD; ++e0)
            acc += bb[h * DD + e0] * A[(h * DD + dout) * DD + e0];
        bo[j] = acc;
    }
}

// ================= CSR build: bucketed two-phase counting sort =================
__global__ __launch_bounds__(256) void bucket_hist(
    const int* __restrict__ p0, const int* __restrict__ p1, const int* __restrict__ p2,
    const int* __restrict__ p3, const int* __restrict__ p4, int* __restrict__ bcnt)
{
    int r = blockIdx.y;
    const int* col = sel_edge(r, p0, p1, p2, p3, p4) + EE;
    __shared__ int lh[256];
    int tid = threadIdx.x;
    lh[tid] = 0;
    __syncthreads();
    int base = blockIdx.x * 4096;
    for (int i = tid; i < 4096; i += 256) {
        int g = base + i;
        if (g < EE) atomicAdd(&lh[col[g] >> 9], 1);
    }
    __syncthreads();
    if (tid < NB && lh[tid]) atomicAdd(&bcnt[r * NB + tid], lh[tid]);
}

__global__ __launch_bounds__(256) void bucket_scan(
    const int* __restrict__ bcnt, int* __restrict__ bbase, int* __restrict__ gcur,
    int* __restrict__ indptr)
{
    int r = blockIdx.x;
    __shared__ int ls[256];
    int tid = threadIdx.x;
    ls[tid] = (tid < NB) ? bcnt[r * NB + tid] : 0;
    __syncthreads();
    for (int o = 1; o < 256; o <<= 1) {
        int v = (tid >= o) ? ls[tid - o] : 0;
        __syncthreads();
        ls[tid] += v;
        __syncthreads();
    }
    int ex = (tid == 0) ? 0 : ls[tid - 1];
    if (tid < NB) {
        bbase[r * (NB + 1) + tid] = ex;
        gcur[r * NB + tid] = ex;
    }
    if (tid == NB) bbase[r * (NB + 1) + NB] = ls[NB - 1];   // == EE
    if (tid == 0) indptr[(size_t)r * (NN + 1) + NN] = EE;
}

// P2: partition packed (col_local<<17 | row) into bucket-contiguous runs
__global__ __launch_bounds__(256) void bucket_partition(
    const int* __restrict__ p0, const int* __restrict__ p1, const int* __restrict__ p2,
    const int* __restrict__ p3, const int* __restrict__ p4,
    int* __restrict__ gcur, unsigned* __restrict__ pairs)
{
    int r = blockIdx.y;
    const int* ebase = sel_edge(r, p0, p1, p2, p3, p4);
    const int* colp = ebase + EE;
    __shared__ int2 stag[4096];
    __shared__ int lh[256], lofs[256], lcur[256], gpos[256];
    int tid = threadIdx.x;
    lh[tid] = 0;
    __syncthreads();
    int base = blockIdx.x * 4096;
    for (int i = tid; i < 4096; i += 256) {
        int g = base + i;
        if (g < EE) atomicAdd(&lh[colp[g] >> 9], 1);
    }
    __syncthreads();
    lofs[tid] = lh[tid];
    __syncthreads();
    for (int o = 1; o < 256; o <<= 1) {
        int v = (tid >= o) ? lofs[tid - o] : 0;
        __syncthreads();
        lofs[tid] += v;
        __syncthreads();
    }
    int ex = (tid == 0) ? 0 : lofs[tid - 1];
    __syncthreads();
    lofs[tid] = ex;
    lcur[tid] = ex;
    gpos[tid] = (lh[tid] > 0) ? atomicAdd(&gcur[r * NB + tid], lh[tid]) : 0;
    __syncthreads();
    for (int i = tid; i < 4096; i += 256) {
        int g = base + i;
        if (g < EE) {
            int c = colp[g];
            int b = c >> 9;
            int s = atomicAdd(&lcur[b], 1);
            stag[s] = make_int2(ebase[g], c);
        }
    }
    __syncthreads();
    int total = EE - base; if (total > 4096) total = 4096;
    for (int s = tid; s < total; s += 256) {
        int2 pr = stag[s];
        int b = pr.y >> 9;
        unsigned packed = ((unsigned)(pr.y & 511) << 17) | (unsigned)pr.x;
        pairs[(size_t)r * EE + gpos[b] + (s - lofs[b])] = packed;
    }
}

__global__ __launch_bounds__(256) void bucket_finalize(
    const unsigned* __restrict__ pairs, const int* __restrict__ bbase,
    int* __restrict__ indptr, int* __restrict__ rowsrt)
{
    int r = blockIdx.y, b = blockIdx.x;
    int beg = bbase[r * (NB + 1) + b], end = bbase[r * (NB + 1) + b + 1];
    int d0 = b << 9;
    int nd = NN - d0; if (nd > 512) nd = 512;
    __shared__ int cnt[512];
    __shared__ int exc[512];
    __shared__ int ls[256];
    int tid = threadIdx.x;
    cnt[tid] = 0; cnt[tid + 256] = 0;
    __syncthreads();
    const unsigned* pp = pairs + (size_t)r * EE;
    for (int e = beg + tid; e < end; e += 256)
        atomicAdd(&cnt[pp[e] >> 17], 1);
    __syncthreads();
    int a0 = cnt[2 * tid], a1 = cnt[2 * tid + 1];
    ls[tid] = a0 + a1;
    __syncthreads();
    for (int o = 1; o < 256; o <<= 1) {
        int v = (tid >= o) ? ls[tid - o] : 0;
        __syncthreads();
        ls[tid] += v;
        __syncthreads();
    }
    int ex2 = (tid == 0) ? 0 : ls[tid - 1];
    exc[2 * tid] = ex2;
    exc[2 * tid + 1] = ex2 + a0;
    __syncthreads();
    for (int i = tid; i < nd; i += 256)
        indptr[(size_t)r * (NN + 1) + d0 + i] = beg + exc[i];
    cnt[2 * tid] = exc[2 * tid];
    cnt[2 * tid + 1] = exc[2 * tid + 1];
    __syncthreads();
    for (int e = beg + tid; e < end; e += 256) {
        unsigned pr = pp[e];
        int p = atomicAdd(&cnt[pr >> 17], 1);
        rowsrt[(size_t)r * EE + beg + p] = (int)(pr & 0x1FFFFu);
    }
}

// ====== degree-sorted node order — contention-free (block-local hist + range reserve) ===
__global__ __launch_bounds__(256) void deg_hist(const int* __restrict__ indptr,
                                                int* __restrict__ dbin)
{
    int r = blockIdx.y;
    __shared__ int lh[256];
    int tid = threadIdx.x;
    lh[tid] = 0;
    __syncthreads();
    int i = blockIdx.x * 256 + tid;
    if (i < NN) {
        const int* ip = indptr + (size_t)r * (NN + 1);
        int deg = ip[i + 1] - ip[i];
        if (deg > 255) deg = 255;
        atomicAdd(&lh[deg], 1);             // LDS atomic: fast
    }
    __syncthreads();
    if (lh[tid]) atomicAdd(&dbin[r * 256 + tid], lh[tid]);   // 1 global atomic / bin / block
}

__global__ __launch_bounds__(256) void deg_scan(int* __restrict__ dbin)
{
    int r = blockIdx.x;
    __shared__ int ls[256];
    int tid = threadIdx.x;
    ls[tid] = dbin[r * 256 + tid];
    __syncthreads();
    for (int o = 1; o < 256; o <<= 1) {
        int v = (tid >= o) ? ls[tid - o] : 0;
        __syncthreads();
        ls[tid] += v;
        __syncthreads();
    }
    dbin[r * 256 + tid] = (tid == 0) ? 0 : ls[tid - 1];   // exclusive -> cursor
}

__global__ __launch_bounds__(256) void deg_scatter(const int* __restrict__ indptr,
                                                   int* __restrict__ dbin,
                                                   int* __restrict__ order)
{
    int r = blockIdx.y;
    __shared__ int lh[256], gpos[256], lcur[256];
    int tid = threadIdx.x;
    lh[tid] = 0;
    __syncthreads();
    int i = blockIdx.x * 256 + tid;
    int deg = -1;
    if (i < NN) {
        const int* ip = indptr + (size_t)r * (NN + 1);
        deg = ip[i + 1] - ip[i];
        if (deg > 255) deg = 255;
        atomicAdd(&lh[deg], 1);
    }
    __syncthreads();
    gpos[tid] = (lh[tid] > 0) ? atomicAdd(&dbin[r * 256 + tid], lh[tid]) : 0;
    lcur[tid] = 0;
    __syncthreads();
    if (i < NN) {
        int p = atomicAdd(&lcur[deg], 1);   // LDS atomic
        order[(size_t)r * NN + gpos[deg] + p] = i;
    }
}

// ---------------- fused K+V projection (per TYPE) -> KV[node][0:64]=K, [64:128]=V ------
__global__ __launch_bounds__(256) void projKV_kernel(
    const float* __restrict__ X,
    const float* __restrict__ WK, const float* __restrict__ BK,
    const float* __restrict__ WV, const float* __restrict__ BV,
    float* __restrict__ KV, int nrows)
{
    __shared__ float Xs[PR][CC + 1];
    __shared__ float WKs[CC][CC];
    __shared__ float WVs[CC][CC];
    __shared__ float bks[CC], bvs[CC];
    int tid = threadIdx.x;
    int row0 = blockIdx.x * PR;
    for (int i = tid; i < CC * CC; i += 256) {
        WKs[i >> 6][i & 63] = WK[i];
        WVs[i >> 6][i & 63] = WV[i];
    }
    if (tid < CC) { bks[tid] = BK[tid]; bvs[tid] = BV[tid]; }
    for (int i = tid; i < PR * CC; i += 256) {
        int r = i >> 6, c = i & 63;
        int gr = row0 + r;
        Xs[r][c] = (gr < nrows) ? X[(size_t)gr * CC + c] : 0.f;
    }
    __syncthreads();
    int tx = tid & 15, ty = tid >> 4;
    float aK[4][4], aV[4][4];
    #pragma unroll
    for (int i = 0; i < 4; ++i)
        #pragma unroll
        for (int j = 0; j < 4; ++j) { aK[i][j] = 0.f; aV[i][j] = 0.f; }
    for (int k = 0; k < CC; ++k) {
        float xv[4], wk4[4], wv4[4];
        #pragma unroll
        for (int i = 0; i < 4; ++i) xv[i] = Xs[ty + 16 * i][k];
        #pragma unroll
        for (int j = 0; j < 4; ++j) { wk4[j] = WKs[k][tx + 16 * j]; wv4[j] = WVs[k][tx + 16 * j]; }
        #pragma unroll
        for (int i = 0; i < 4; ++i)
            #pragma unroll
            for (int j = 0; j < 4; ++j) {
                aK[i][j] += xv[i] * wk4[j];
                aV[i][j] += xv[i] * wv4[j];
            }
    }
    #pragma unroll
    for (int i = 0; i < 4; ++i) {
        int r = row0 + ty + 16 * i;
        if (r < nrows) {
            #pragma unroll
            for (int j = 0; j < 4; ++j) {
                int c = tx + 16 * j;
                KV[(size_t)r * 128 + c]      = aK[i][j] + bks[c];
                KV[(size_t)r * 128 + 64 + c] = aV[i][j] + bvs[c];
            }
        }
    }
}

// ---------------- edge pass: degree-sorted nodes; 4 dst nodes/wave ---------------------
__global__ __launch_bounds__(256) void edge_kernel(
    const int* __restrict__ indptr_all, const int* __restrict__ rows_all,
    const int* __restrict__ order_all,
    const float* __restrict__ x0, const float* __restrict__ x1, const float* __restrict__ x2,
    const float* __restrict__ WQE_l, const float* __restrict__ BQE_l,
    const float* __restrict__ kv, const float* __restrict__ Mrel_l,
    const float* __restrict__ prel_l,
    float* __restrict__ outb, int r0)
{
    int ri = blockIdx.y;
    int r = r0 + ri;
    int d = g_dst[r];
    const float* xd = (d == 0) ? x0 : (d == 1) ? x1 : x2;
    const int* indptr = indptr_all + (size_t)r * (NN + 1);
    const int* rows = rows_all + (size_t)r * EE;
    const int* order = order_all + (size_t)r * NN;
    const float* Wq = WQE_l + (size_t)ri * CC * CC;
    const float* bqp = BQE_l + (size_t)ri * CC;
    const float* Mrel = Mrel_l + (size_t)ri * HH * DD * DD;
    const float* prel = prel_l + (size_t)ri * HH;
    float* outp = outb + (size_t)d * NN * CC;
    int accum = 1 - g_first[r];

    __shared__ float4 Wq4s[CC][16];    // 16 KB
    __shared__ float  xs[16][CC + 4];  // padded: groups hit distinct banks
    __shared__ float4 bq4s[16];
    int tid = threadIdx.x;
    const float4* Wq4 = (const float4*)Wq;
    for (int i = tid; i < CC * 16; i += 256)
        Wq4s[i >> 4][i & 15] = Wq4[i];
    if (tid < 16) bq4s[tid] = ((const float4*)bqp)[tid];

    int g = tid >> 4;                 // node slot 0..15
    int gl = tid & 15;                // lane in group: channels 4gl..4gl+3
    int node = order[blockIdx.x * 16 + g];   // degree-sorted permutation
    {
        float4 xv4 = ((const float4*)xd)[(size_t)node * 16 + gl];
        ((float4*)&xs[g][0])[gl] = xv4;
    }
    __syncthreads();

    int h = gl >> 2;
    float ps = prel[h] * (0.25f * 1.4426950408889634f);

    float4 q4 = bq4s[gl];
    #pragma unroll 8
    for (int k = 0; k < CC; ++k) {
        float xk = xs[g][k];
        float4 w = Wq4s[k][gl];
        q4.x += xk * w.x; q4.y += xk * w.y; q4.z += xk * w.z; q4.w += xk * w.w;
    }

    int beg = indptr[node], end = indptr[node + 1];
    float m = -INFINITY, ss = 0.f;
    float4 o4 = make_float4(0.f, 0.f, 0.f, 0.f);
    const float4* kv4 = (const float4*)kv;
    for (int e = beg; e < end; ++e) {
        int rr = rows[e];
        const float4* kp = kv4 + (size_t)rr * 32;
        float4 k4 = kp[gl];
        float4 v4 = kp[16 + gl];
        float p = q4.x * k4.x + q4.y * k4.y + q4.z * k4.z + q4.w * k4.w;
        p += __shfl_xor(p, 1, 4);
        p += __shfl_xor(p, 2, 4);
        float al = p * ps;
        float nm = fmaxf(m, al);
        float sc = exp2f(m - nm);
        float ei = exp2f(al - nm);
        ss = ss * sc + ei;
        o4.x = o4.x * sc + ei * v4.x;
        o4.y = o4.y * sc + ei * v4.y;
        o4.z = o4.z * sc + ei * v4.z;
        o4.w = o4.w * sc + ei * v4.w;
        m = nm;
    }
    float inv = 1.f / (ss + 1e-16f);
    float4 res = make_float4(o4.x * inv, o4.y * inv, o4.z * inv, o4.w * inv);

    // out[h,e] = sum_d res[h,d] * M[h][d][e]  (M from global: 4 KB, L2-hot)
    const float4* Ms4 = (const float4*)Mrel;
    float4 out4 = make_float4(0.f, 0.f, 0.f, 0.f);
    int e4 = gl & 3;
    #pragma unroll
    for (int sl = 0; sl < 4; ++sl) {
        int src = (gl & 12) + sl;
        float a0 = __shfl(res.x, src, 16);
        float a1 = __shfl(res.y, src, 16);
        float a2 = __shfl(res.z, src, 16);
        float a3 = __shfl(res.w, src, 16);
        float4 m0 = Ms4[(h * DD + sl * 4 + 0) * 4 + e4];
        float4 m1 = Ms4[(h * DD + sl * 4 + 1) * 4 + e4];
        float4 m2 = Ms4[(h * DD + sl * 4 + 2) * 4 + e4];
        float4 m3 = Ms4[(h * DD + sl * 4 + 3) * 4 + e4];
        out4.x += a0 * m0.x + a1 * m1.x + a2 * m2.x + a3 * m3.x;
        out4.y += a0 * m0.y + a1 * m1.y + a2 * m2.y + a3 * m3.y;
        out4.z += a0 * m0.z + a1 * m1.z + a2 * m2.z + a3 * m3.z;
        out4.w += a0 * m0.w + a1 * m1.w + a2 * m2.w + a3 * m3.w;
    }

    float4* op = (float4*)outp + (size_t)node * 16;
    if (accum) {
        float4 old = op[gl];
        out4.x += old.x; out4.y += old.y; out4.z += old.z; out4.w += old.w;
    }
    op[gl] = out4;
}

// ---------------- post: 64-row GEMM tile + fused skip/LN/gelu --------------------------
__global__ __launch_bounds__(256) void post3_kernel(
    const float* __restrict__ x0, const float* __restrict__ x1, const float* __restrict__ x2,
    const float* __restrict__ outc, float* __restrict__ xout,
    const float* __restrict__ Wa_l, const float* __restrict__ ba_l,
    const float* __restrict__ skp_l,
    const float* __restrict__ lnw_l, const float* __restrict__ lnb_l)
{
    int t = blockIdx.y;
    const float* xin = (t == 0) ? x0 : (t == 1) ? x1 : x2;
    const float* Wa = Wa_l + (size_t)t * CC * CC;
    const float* ba = ba_l + (size_t)t * CC;
    const float* lnw = lnw_l + (size_t)t * CC;
    const float* lnb = lnb_l + (size_t)t * CC;
    const float* oc = outc + (size_t)t * NN * CC;
    float* xo = xout + (size_t)t * NN * CC;

    __shared__ float Gs[PR][CC + 1];
    __shared__ float Was[CC][CC];
    __shared__ float bas[CC], lnws[CC], lnbs[CC];
    int tid = threadIdx.x;
    int row0 = blockIdx.x * PR;
    for (int i = tid; i < CC * CC; i += 256) Was[i >> 6][i & 63] = Wa[i];
    if (tid < CC) { bas[tid] = ba[tid]; lnws[tid] = lnw[tid]; lnbs[tid] = lnb[tid]; }
    for (int i = tid; i < PR * CC; i += 256) {
        int r = i >> 6, c = i & 63;
        int gr = row0 + r;
        Gs[r][c] = (gr < NN) ? geluf(oc[(size_t)gr * CC + c]) : 0.f;
    }
    __syncthreads();
    int tx = tid & 15, ty = tid >> 4;
    float acc[4][4];
    #pragma unroll
    for (int i = 0; i < 4; ++i)
        #pragma unroll
        for (int j = 0; j < 4; ++j) acc[i][j] = 0.f;
    for (int k = 0; k < CC; ++k) {
        float gv[4], w4[4];
        #pragma unroll
        for (int i = 0; i < 4; ++i) gv[i] = Gs[ty + 16 * i][k];
        #pragma unroll
        for (int j = 0; j < 4; ++j) w4[j] = Was[k][tx + 16 * j];
        #pragma unroll
        for (int i = 0; i < 4; ++i)
            #pragma unroll
            for (int j = 0; j < 4; ++j) acc[i][j] += gv[i] * w4[j];
    }
    float a = 1.f / (1.f + expf(-skp_l[t]));
    #pragma unroll
    for (int i = 0; i < 4; ++i) {
        int r = row0 + ty + 16 * i;
        if (r >= NN) continue;
        float vals[4];
        float s1 = 0.f;
        #pragma unroll
        for (int j = 0; j < 4; ++j) {
            int c = tx + 16 * j;
            float o = a * (acc[i][j] + bas[c]) + (1.f - a) * xin[(size_t)r * CC + c];
            vals[j] = o;
            s1 += o;
        }
        s1 += __shfl_xor(s1, 1, 16);
        s1 += __shfl_xor(s1, 2, 16);
        s1 += __shfl_xor(s1, 4, 16);
        s1 += __shfl_xor(s1, 8, 16);
        float mean = s1 * (1.f / 64.f);
        float s2 = 0.f;
        #pragma unroll
        for (int j = 0; j < 4; ++j) {
            float dc = vals[j] - mean;
            s2 += dc * dc;
        }
        s2 += __shfl_xor(s2, 1, 16);
        s2 += __shfl_xor(s2, 2, 16);
        s2 += __shfl_xor(s2, 4, 16);
        s2 += __shfl_xor(s2, 8, 16);
        float inv = 1.f / sqrtf(s2 * (1.f / 64.f) + 1e-5f);
        #pragma unroll
        for (int j = 0; j < 4; ++j) {
            int c = tx + 16 * j;
            float y = (vals[j] - mean) * inv * lnws[c] + lnbs[c];
            xo[(size_t)r * CC + c] = geluf(y);
        }
    }
}

// ---------------- pooling scores: 64-row tile; VGPR-capped (R13: 176 VGPR -> 11% occ) ---
__global__ __launch_bounds__(256, 4) void scores_kernel(const float* __restrict__ X,
                                                        const float* __restrict__ Wfc, const float* __restrict__ bfc,
                                                        const float* __restrict__ Wsc, float* __restrict__ sc)
{
    int t = blockIdx.y;
    __shared__ float Xs[PR][CC + 1];
    __shared__ float Wfs[CC][33];
    __shared__ float bfs[32], wscs[32];
    int tid = threadIdx.x;
    int row0 = blockIdx.x * PR;
    const float* Xt = X + (size_t)t * NN * CC;
    for (int i = tid; i < CC * 32; i += 256) Wfs[i >> 5][i & 31] = Wfc[(size_t)t * CC * 32 + i];
    if (tid < 32) { bfs[tid] = bfc[t * 32 + tid]; wscs[tid] = Wsc[t * 32 + tid]; }
    for (int i = tid; i < PR * CC; i += 256) {
        int r = i >> 6, c = i & 63;
        int gr = row0 + r;
        Xs[r][c] = (gr < NN) ? Xt[(size_t)gr * CC + c] : 0.f;
    }
    __syncthreads();
    int tx = tid & 15, ty = tid >> 4;
    float acc[4][2];
    #pragma unroll
    for (int i = 0; i < 4; ++i) { acc[i][0] = 0.f; acc[i][1] = 0.f; }
    #pragma unroll 4
    for (int k = 0; k < CC; ++k) {
        float w0 = Wfs[k][tx], w1 = Wfs[k][tx + 16];
        #pragma unroll
        for (int i = 0; i < 4; ++i) {
            float xv = Xs[ty + 16 * i][k];
            acc[i][0] += xv * w0;
            acc[i][1] += xv * w1;
        }
    }
    #pragma unroll
    for (int i = 0; i < 4; ++i) {
        float p = geluf(acc[i][0] + bfs[tx]) * wscs[tx]
                + geluf(acc[i][1] + bfs[tx + 16]) * wscs[tx + 16];
        p += __shfl_xor(p, 1, 16);
        p += __shfl_xor(p, 2, 16);
        p += __shfl_xor(p, 4, 16);
        p += __shfl_xor(p, 8, 16);
        int r = row0 + ty + 16 * i;
        if (tx == 0 && r < NN) sc[(size_t)t * NN + r] = p;
    }
}

// ---------------- top-8 (jax tie semantics: value desc, then lower index) ----------------
#define CHUNK 1250
__global__ __launch_bounds__(256) void topk1(const float* __restrict__ sc, float* __restrict__ candv,
                                             int* __restrict__ candi, int total)
{
    __shared__ float v[CHUNK];
    __shared__ float rv[256];
    __shared__ int ri[256];
    int tid = threadIdx.x;
    int base = blockIdx.x * CHUNK;
    for (int i = tid; i < CHUNK; i += 256) {
        int g = base + i;
        v[i] = (g < total) ? sc[g] : -INFINITY;
    }
    __syncthreads();
    for (int it = 0; it < 8; ++it) {
        float bv = v[tid]; int bi = tid;
        for (int i = tid + 256; i < CHUNK; i += 256) {
            float x = v[i];
            if (x > bv) { bv = x; bi = i; }
        }
        rv[tid] = bv; ri[tid] = bi;
        __syncthreads();
        for (int s2 = 128; s2 > 0; s2 >>= 1) {
            if (tid < s2) {
                float ov = rv[tid + s2]; int oi = ri[tid + s2];
                if (ov > rv[tid] || (ov == rv[tid] && oi < ri[tid])) { rv[tid] = ov; ri[tid] = oi; }
            }
            __syncthreads();
        }
        if (tid == 0) {
            candv[blockIdx.x * 8 + it] = rv[0];
            candi[blockIdx.x * 8 + it] = base + ri[0];
            v[ri[0]] = -INFINITY;
        }
        __syncthreads();
    }
}

#define NCAND 1920
__global__ __launch_bounds__(256) void topk2(const float* __restrict__ candv, const int* __restrict__ candi,
                                             float* __restrict__ topv, int* __restrict__ topi)
{
    __shared__ float v[NCAND];
    __shared__ int gi[NCAND];
    __shared__ float rv[256];
    __shared__ int ri[256];
    int tid = threadIdx.x;
    for (int i = tid; i < NCAND; i += 256) { v[i] = candv[i]; gi[i] = candi[i]; }
    __syncthreads();
    for (int it = 0; it < 8; ++it) {
        float bv = v[tid]; int bs = tid;
        for (int i = tid + 256; i < NCAND; i += 256) {
            float x = v[i];
            if (x > bv || (x == bv && gi[i] < gi[bs])) { bv = x; bs = i; }
        }
        rv[tid] = bv; ri[tid] = bs;
        __syncthreads();
        for (int s2 = 128; s2 > 0; s2 >>= 1) {
            if (tid < s2) {
                float ov = rv[tid + s2]; int os = ri[tid + s2];
                if (ov > rv[tid] || (ov == rv[tid] && gi[os] < gi[ri[tid]])) { rv[tid] = ov; ri[tid] = os; }
            }
            __syncthreads();
        }
        if (tid == 0) {
            topv[it] = rv[0];
            topi[it] = gi[ri[0]];
            v[ri[0]] = -INFINITY;
        }
        __syncthreads();
    }
}

// ---------------- final: recompute z for winners, pooled, MLP head ----------------
__global__ __launch_bounds__(256) void mlp_kernel(const float* __restrict__ X,
    const float* __restrict__ Wfc, const float* __restrict__ bfc,
    const float* __restrict__ topv, const int* __restrict__ topi,
    const float* __restrict__ W1, const float* __restrict__ b1,
    const float* __restrict__ W2, const float* __restrict__ b2,
    const float* __restrict__ W3, const float* __restrict__ b3,
    const float* __restrict__ W4, const float* __restrict__ b4,
    float* __restrict__ out)
{
    __shared__ float h0[256], h1[128], h2[64], h3[32];
    int tid = threadIdx.x;
    int wv = tid >> 6, lane = tid & 63;
    int j = lane & 31, half = lane >> 5;
    for (int w = wv; w < 8; w += 4) {
        int gidx = topi[w];
        float ts = topv[w];
        const float* xr = X + (size_t)gidx * 64;
        int t = gidx / NN;
        const float* Wf = Wfc + (size_t)t * CC * 32;
        float acc = 0.f;
        #pragma unroll
        for (int k2 = 0; k2 < 32; ++k2) {
            int k = half * 32 + k2;
            acc += xr[k] * Wf[k * 32 + j];
        }
        acc += __shfl_xor(acc, 32, 64);
        float z = geluf(acc + bfc[t * 32 + j]);
        if (half == 0) h0[w * 32 + j] = z * tanhf(ts);
    }
    __syncthreads();
    if (tid < 128) {
        float a = b1[tid];
        for (int k = 0; k < 256; ++k) a += h0[k] * W1[k * 128 + tid];
        h1[tid] = geluf(a);
    }
    __syncthreads();
    if (tid < 64) {
        float a = b2[tid];
        for (int k = 0; k < 128; ++k) a += h1[k] * W2[k * 64 + tid];
        h2[tid] = geluf(a);
    }
    __syncthreads();
    if (tid < 32) {
        float a = b3[tid];
        for (int k = 0; k < 64; ++k) a += h2[k] * W3[k * 32 + tid];
        h3[tid] = geluf(a);
    }
    __syncthreads();
    if (tid == 0) {
        float a = b4[0];
        for (int k = 0; k < 32; ++k) a += h3[k] * W4[k];
        if (isnan(a)) a = 0.f;
        else if (isinf(a)) a = (a > 0.f) ? FLT_MAX : -FLT_MAX;
        out[0] = a;
    }
}

extern "C" void kernel_launch(void* const* d_in, const int* in_sizes, int n_in,
                              void* d_out, int out_size, void* d_ws, size_t ws_size,
                              hipStream_t stream)
{
    (void)in_sizes; (void)n_in; (void)out_size;
    static const int h_r0[TT]   = {0, 2, 4};
    static const int h_nrel[TT] = {2, 2, 1};

    const float* xin0[TT] = {(const float*)d_in[0], (const float*)d_in[1], (const float*)d_in[2]};
    const int* ei[RR];
    for (int r = 0; r < RR; ++r) ei[r] = (const int*)d_in[3 + r];
    const float* Wk   = (const float*)d_in[8];
    const float* bk   = (const float*)d_in[9];
    const float* Wq   = (const float*)d_in[10];
    const float* bq   = (const float*)d_in[11];
    const float* Wv   = (const float*)d_in[12];
    const float* bv   = (const float*)d_in[13];
    const float* Wa   = (const float*)d_in[14];
    const float* ba   = (const float*)d_in[15];
    const float* skp  = (const float*)d_in[16];
    const float* lnw  = (const float*)d_in[17];
    const float* lnb  = (const float*)d_in[18];
    const float* a_rel = (const float*)d_in[19];
    const float* m_rel = (const float*)d_in[20];
    const float* p_rel = (const float*)d_in[21];
    const float* Wfc  = (const float*)d_in[22];
    const float* bfc  = (const float*)d_in[23];
    const float* Wsc  = (const float*)d_in[24];
    const float* W1 = (const float*)d_in[25]; const float* b1 = (const float*)d_in[26];
    const float* W2 = (const float*)d_in[27]; const float* b2 = (const float*)d_in[28];
    const float* W3 = (const float*)d_in[29]; const float* b3 = (const float*)d_in[30];
    const float* W4 = (const float*)d_in[31]; const float* b4 = (const float*)d_in[32];

    char* ws = (char*)d_ws;
    size_t off = 0;
    auto alloc = [&](size_t bytes) -> char* {
        char* p = ws + off;
        off = (off + bytes + 255) & ~(size_t)255;
        return p;
    };
    float* Xb   = (float*)alloc((size_t)TT * NN * CC * 4);   // 76.8 MB
    float* OUTb = (float*)alloc((size_t)TT * NN * CC * 4);   // 76.8 MB (pairs aliased here)
    float* KVb  = (float*)alloc((size_t)NN * 128 * 4);       // 51.2 MB  [node][K|V]
    float* WQE  = (float*)alloc((size_t)LL * RR * CC * CC * 4);  // 1.3 MB
    float* BQE  = (float*)alloc((size_t)LL * RR * CC * 4);
    int* indptr = (int*)alloc((size_t)RR * (NN + 1) * 4);    // 2.0 MB
    int* rowsrt = (int*)alloc((size_t)RR * EE * 4);          // 20.0 MB
    int* order  = (int*)alloc((size_t)RR * NN * 4);          // 2.0 MB degree-sorted node ids
    int* bcnt   = (int*)alloc((size_t)RR * NB * 4);
    int* bbase  = (int*)alloc((size_t)RR * (NB + 1) * 4);
    int* gcur   = (int*)alloc((size_t)RR * NB * 4);
    int* dbin   = (int*)alloc((size_t)RR * 256 * 4);
    float* scb  = (float*)alloc((size_t)TT * NN * 4);
    float* candv = (float*)alloc(240 * 8 * 4);
    int* candi   = (int*)alloc(240 * 8 * 4);
    float* topv  = (float*)alloc(64);
    int* topi    = (int*)alloc(64);
    unsigned* pairs = (unsigned*)OUTb;   // 20 MB alias; CSR build finishes before OUTb is used

    if (off > ws_size) {
        zero_out_kernel<<<1, 64, 0, stream>>>((float*)d_out);
        return;
    }

    // fold a_rel^T into the per-relation Q weights
    fuse_q<<<LL * RR, 256, 0, stream>>>(Wq, bq, a_rel, WQE, BQE);

    // ---- CSR build (bucketed two-phase counting sort), all 5 relations ----
    const int chunkGrid = (EE + 4095) / 4096;   // 245
    const int nGrid = (NN + 255) / 256;         // 391
    hipMemsetAsync(bcnt, 0, (size_t)RR * NB * 4, stream);
    bucket_hist<<<dim3(chunkGrid, RR), 256, 0, stream>>>(ei[0], ei[1], ei[2], ei[3], ei[4], bcnt);
    bucket_scan<<<RR, 256, 0, stream>>>(bcnt, bbase, gcur, indptr);
    bucket_partition<<<dim3(chunkGrid, RR), 256, 0, stream>>>(ei[0], ei[1], ei[2], ei[3], ei[4],
                                                              gcur, pairs);
    bucket_finalize<<<dim3(NB, RR), 256, 0, stream>>>(pairs, bbase, indptr, rowsrt);

    // ---- degree-sorted node order per relation (contention-free two-phase sort) ----
    hipMemsetAsync(dbin, 0, (size_t)RR * 256 * 4, stream);
    deg_hist<<<dim3(nGrid, RR), 256, 0, stream>>>(indptr, dbin);
    deg_scan<<<RR, 256, 0, stream>>>(dbin);
    deg_scatter<<<dim3(nGrid, RR), 256, 0, stream>>>(indptr, dbin, order);

    const int gproj = (NN + PR - 1) / PR;                   // 1563
    const int gedge = NN / 16;                              // 6250 (exact)
    const float* xcur[TT] = {xin0[0], xin0[1], xin0[2]};

    for (int l = 0; l < LL; ++l) {
        for (int s = 0; s < TT; ++s) {
            projKV_kernel<<<gproj, 256, 0, stream>>>(xcur[s],
                Wk + (size_t)(l * TT + s) * CC * CC, bk + (size_t)(l * TT + s) * CC,
                Wv + (size_t)(l * TT + s) * CC * CC, bv + (size_t)(l * TT + s) * CC,
                KVb, NN);
            int r0 = h_r0[s];
            int lr0 = l * RR + r0;
            edge_kernel<<<dim3(gedge, h_nrel[s]), 256, 0, stream>>>(
                indptr, rowsrt, order, xcur[0], xcur[1], xcur[2],
                WQE + (size_t)lr0 * CC * CC, BQE + (size_t)lr0 * CC,
                KVb, m_rel + (size_t)lr0 * HH * DD * DD, p_rel + (size_t)lr0 * HH,
                OUTb, r0);
        }
        post3_kernel<<<dim3(gproj, TT), 256, 0, stream>>>(xcur[0], xcur[1], xcur[2],
            OUTb, Xb,
            Wa + (size_t)l * TT * CC * CC, ba + (size_t)l * TT * CC,
            skp + l * TT,
            lnw + (size_t)l * TT * CC, lnb + (size_t)l * TT * CC);
        for (int t = 0; t < TT; ++t) xcur[t] = Xb + (size_t)t * NN * CC;
    }

    scores_kernel<<<dim3(gproj, TT), 256, 0, stream>>>(Xb, Wfc, bfc, Wsc, scb);
    topk1<<<240, 256, 0, stream>>>(scb, candv, candi, TT * NN);
    topk2<<<1, 256, 0, stream>>>(candv, candi, topv, topi);
    mlp_kernel<<<1, 256, 0, stream>>>(Xb, Wfc, bfc, topv, topi,
                                      W1, b1, W2, b2, W3, b3, W4, b4, (float*)d_out);
}